// Round 1
// baseline (406.147 us; speedup 1.0000x reference)
//
#include <hip/hip_runtime.h>
#include <hip/hip_bf16.h>
#include <math.h>

typedef __bf16 bf16_8 __attribute__((ext_vector_type(8)));
typedef __bf16 bf16_4 __attribute__((ext_vector_type(4)));
typedef float f32x4 __attribute__((ext_vector_type(4)));

// ---------------------------------------------------------------- LayerNorm (fp32 in -> bf16 out)
__global__ __launch_bounds__(256) void ln_kernel(
    const float* __restrict__ x, const float* __restrict__ g,
    const float* __restrict__ b, __hip_bfloat16* __restrict__ out, int cols) {
  const int row = blockIdx.x;
  const int t = threadIdx.x;
  float loc[3];
  float s = 0.f, s2 = 0.f;
#pragma unroll
  for (int i = 0; i < 3; ++i) {
    float v = x[(size_t)row * cols + t + i * 256];
    loc[i] = v;
    s += v;
    s2 += v * v;
  }
#pragma unroll
  for (int off = 32; off; off >>= 1) {
    s += __shfl_down(s, off);
    s2 += __shfl_down(s2, off);
  }
  __shared__ float red[2][4];
  const int lane = t & 63, w = t >> 6;
  if (lane == 0) {
    red[0][w] = s;
    red[1][w] = s2;
  }
  __syncthreads();
  s = red[0][0] + red[0][1] + red[0][2] + red[0][3];
  s2 = red[1][0] + red[1][1] + red[1][2] + red[1][3];
  const float mu = s / cols;
  const float var = s2 / cols - mu * mu;
  const float rs = rsqrtf(var + 1e-5f);
  __hip_bfloat16* orow = out + (size_t)row * cols;
#pragma unroll
  for (int i = 0; i < 3; ++i) {
    int c = t + i * 256;
    orow[c] = __hip_bfloat16((loc[i] - mu) * rs * g[c] + b[c]);
  }
}

// ---------------------------------------------------------------- fp32 -> bf16 weight conversion
// grid = (n/1024, nsrc); each of the nsrc matrices has exactly n elements (n % 1024 == 0).
__global__ __launch_bounds__(256) void cvt_multi(
    const float* __restrict__ sa, const float* __restrict__ sb,
    const float* __restrict__ sc, const float* __restrict__ sd,
    __hip_bfloat16* __restrict__ da, __hip_bfloat16* __restrict__ db,
    __hip_bfloat16* __restrict__ dc, __hip_bfloat16* __restrict__ dd) {
  const float* src;
  __hip_bfloat16* dst;
  if (blockIdx.y == 0) { src = sa; dst = da; }
  else if (blockIdx.y == 1) { src = sb; dst = db; }
  else if (blockIdx.y == 2) { src = sc; dst = dc; }
  else { src = sd; dst = dd; }
  const size_t i = ((size_t)blockIdx.x * 256 + threadIdx.x) * 4;
  float4 f = *(const float4*)(src + i);
  bf16_4 o;
  o[0] = (__bf16)f.x; o[1] = (__bf16)f.y; o[2] = (__bf16)f.z; o[3] = (__bf16)f.w;
  *(bf16_4*)((__bf16*)dst + i) = o;
}

// ---------------------------------------------------------------- GEMM: C = A[M,K] @ B[N,K]^T (both bf16)
// m97 structure: 128x128 tile, BK=64, global_load_lds dwordx4 staging, 2-barrier loop.
// MODE 0 (QKV):  out bf16 split into 3 contiguous [M,768] slots by n/768
// MODE 1 (GELU): out bf16 = gelu_erf(acc + bias[col]), ldout = N
// MODE 2 (ACC):  split-K over gridDim.z; atomicAdd fp32 into out[row*768+col]; bias at z==0
template <int MODE>
__global__ __launch_bounds__(256) void gemm_bt(
    const __hip_bfloat16* __restrict__ A, const __hip_bfloat16* __restrict__ B,
    const float* __restrict__ bias, void* __restrict__ out,
    int M, int N, int K, int lda, int ldb, int ldout) {
  constexpr int BM = 128, BN = 128, BK = 64;
  __shared__ __align__(16) __bf16 As[BM * BK];
  __shared__ __align__(16) __bf16 Bs[BN * BK];
  const int tid = threadIdx.x;
  const int m0 = blockIdx.y * BM;
  const int n0 = blockIdx.x * BN;
  const int wave = tid >> 6;
  const int lane = tid & 63;
  const int quad = lane >> 4;
  const int l16 = lane & 15;
  const int wm = (wave & 1) * 64;
  const int wn = (wave >> 1) * 64;

  int kbase = 0, kcnt = K;
  if constexpr (MODE == 2) {
    kcnt = K / gridDim.z;
    kbase = blockIdx.z * kcnt;
  }

  // global_load_lds staging geometry: each call, a wave writes 1 KiB = 8 rows of 64 bf16.
  // LDS dest = wave-uniform base + lane*16; global src per-lane must match that order:
  // lane l -> row (l>>3), k-chunk (l&7)*8.
  const int srow = lane >> 3;
  const int scol = (lane & 7) * 8;
  const __hip_bfloat16* Ap = A + (size_t)(m0 + wave * 8 + srow) * lda + kbase + scol;
  const __hip_bfloat16* Bp = B + (size_t)(n0 + wave * 8 + srow) * ldb + kbase + scol;

  f32x4 acc[4][4] = {};

  for (int k0 = 0; k0 < kcnt; k0 += BK) {
    __syncthreads();  // previous tile's ds_reads done before overwrite
#pragma unroll
    for (int u = 0; u < 4; ++u) {
      __builtin_amdgcn_global_load_lds(
          (const __attribute__((address_space(1))) void*)(Ap + (size_t)(u * 32) * lda + k0),
          (__attribute__((address_space(3))) void*)(&As[(u * 32 + wave * 8) * BK]), 16, 0, 0);
      __builtin_amdgcn_global_load_lds(
          (const __attribute__((address_space(1))) void*)(Bp + (size_t)(u * 32) * ldb + k0),
          (__attribute__((address_space(3))) void*)(&Bs[(u * 32 + wave * 8) * BK]), 16, 0, 0);
    }
    __syncthreads();  // compiler emits vmcnt(0) drain before this barrier
#pragma unroll
    for (int kk = 0; kk < 2; ++kk) {
      bf16_8 af[4], bfr[4];
#pragma unroll
      for (int i = 0; i < 4; ++i)
        af[i] = *(const bf16_8*)(&As[(wm + i * 16 + l16) * BK + kk * 32 + quad * 8]);
#pragma unroll
      for (int j = 0; j < 4; ++j)
        bfr[j] = *(const bf16_8*)(&Bs[(wn + j * 16 + l16) * BK + kk * 32 + quad * 8]);
#pragma unroll
      for (int i = 0; i < 4; ++i)
#pragma unroll
        for (int j = 0; j < 4; ++j)
          acc[i][j] =
              __builtin_amdgcn_mfma_f32_16x16x32_bf16(af[i], bfr[j], acc[i][j], 0, 0, 0);
    }
  }

  // epilogue: C/D layout col = l16, row = quad*4 + r (verified m89/m91)
#pragma unroll
  for (int i = 0; i < 4; ++i) {
#pragma unroll
    for (int j = 0; j < 4; ++j) {
#pragma unroll
      for (int r = 0; r < 4; ++r) {
        const int row = m0 + wm + i * 16 + quad * 4 + r;
        const int col = n0 + wn + j * 16 + l16;
        const float v = acc[i][j][r];
        if constexpr (MODE == 0) {
          const int tsel = n0 / 768;
          const size_t idx = ((size_t)tsel * M + row) * 768 + (col - tsel * 768);
          ((__hip_bfloat16*)out)[idx] = __hip_bfloat16(v);
        } else if constexpr (MODE == 1) {
          float tt = v + bias[col];
          float gl = 0.5f * tt * (1.0f + erff(tt * 0.70710678118654752f));
          ((__hip_bfloat16*)out)[(size_t)row * ldout + col] = __hip_bfloat16(gl);
        } else {
          float add = v + ((blockIdx.z == 0 && bias) ? bias[col] : 0.f);
          atomicAdd((float*)out + (size_t)row * 768 + col, add);
        }
      }
    }
  }
}

// ---------------------------------------------------------------- work counter
__global__ void zero_ctr(int* __restrict__ c) {
  if (threadIdx.x == 0) *c = 0;
}

// ---------------------------------------------------------------- MFMA flash attention (S^T / O^T form)
// Persistent blocks + atomic work-stealing over heavy-first (qblk desc) tasks.
#define ALDP 72
__global__ __launch_bounds__(256) void attn_mfma(
    const __hip_bfloat16* __restrict__ qb, const __hip_bfloat16* __restrict__ kb,
    const __hip_bfloat16* __restrict__ vb, __hip_bfloat16* __restrict__ ob,
    int* __restrict__ ctr) {
  const int S = 2048, H = 12, E = 768;
  const int tid = threadIdx.x;
  const int wave = tid >> 6;
  const int lane = tid & 63;
  const int quad = lane >> 4;
  const int l16 = lane & 15;

  __shared__ __align__(16) __bf16 Ks[64 * ALDP];     // [key][d]
  __shared__ __align__(16) __bf16 Vt[64 * ALDP];     // [d][key]
  __shared__ __align__(16) __bf16 Pl[4][16 * ALDP];  // wave-private [q][*]
  __shared__ int task;

  for (;;) {
    if (tid == 0) task = atomicAdd(ctr, 1);
    __syncthreads();
    const int t = task;
    if (t >= 24 * 32) return;
    const int qblk = 31 - (t / 24);            // heaviest first
    const int bh = t - (t / 24) * 24;
    const int b = bh / H, h = bh - b * H;
    const int q0 = qblk * 64;
    const int qw = q0 + wave * 16;             // wave's first query
    const size_t base = (size_t)b * S * E + (size_t)h * 64;

    // Q fragments (B-operand: n = q = l16, k = d)
    bf16_8 qf[2];
#pragma unroll
    for (int s = 0; s < 2; ++s)
      qf[s] = *(const bf16_8*)(qb + base + (size_t)(qw + l16) * E + s * 32 + quad * 8);

    f32x4 o[4] = {};              // O^T: row d = dt*16+quad*4+r, col q = l16
    float mq = -1e30f, lq = 0.f;  // per-lane stats for query l16

    for (int kt = 0; kt <= qblk; ++kt) {
      const int k0 = kt * 64;
      __syncthreads();
      // stage K (vector b128) and V transposed (scalar)
#pragma unroll
      for (int u = 0; u < 2; ++u) {
        int i = tid + u * 256;
        int kr = i >> 3, kc = i & 7;
        *(bf16_8*)(&Ks[kr * ALDP + kc * 8]) =
            *(const bf16_8*)(kb + base + (size_t)(k0 + kr) * E + kc * 8);
      }
#pragma unroll
      for (int u = 0; u < 2; ++u) {
        int i = tid + u * 256;
        int kr = i & 63, dq = i >> 6;
        bf16_8 vv = *(const bf16_8*)(vb + base + (size_t)(k0 + kr) * E + dq * 8);
#pragma unroll
        for (int j = 0; j < 8; ++j) Vt[(dq * 8 + j) * ALDP + kr] = vv[j];
      }
      __syncthreads();

      // S^T = K·Q^T
      f32x4 sc[4] = {};
#pragma unroll
      for (int jj = 0; jj < 4; ++jj)
#pragma unroll
        for (int s = 0; s < 2; ++s) {
          bf16_8 kf = *(const bf16_8*)(&Ks[(jj * 16 + l16) * ALDP + s * 32 + quad * 8]);
          sc[jj] = __builtin_amdgcn_mfma_f32_16x16x32_bf16(kf, qf[s], sc[jj], 0, 0, 0);
        }

      // scale + causal mask + per-lane max over the 16 (jj,r) key-scores
      float mx = -1e30f;
#pragma unroll
      for (int jj = 0; jj < 4; ++jj)
#pragma unroll
        for (int r = 0; r < 4; ++r) {
          float v = sc[jj][r] * 0.125f;  // 1/sqrt(64)
          if (kt == qblk && (k0 + jj * 16 + quad * 4 + r) > (qw + l16)) v = -1e30f;
          sc[jj][r] = v;
          mx = fmaxf(mx, v);
        }
      mx = fmaxf(mx, __shfl_xor(mx, 16));
      mx = fmaxf(mx, __shfl_xor(mx, 32));
      const float mn = fmaxf(mq, mx);
      const float corr = __expf(mq - mn);
      mq = mn;
      float sum = 0.f;
#pragma unroll
      for (int jj = 0; jj < 4; ++jj)
#pragma unroll
        for (int r = 0; r < 4; ++r) {
          float p = __expf(sc[jj][r] - mn);
          sc[jj][r] = p;
          sum += p;
        }
      sum += __shfl_xor(sum, 16);
      sum += __shfl_xor(sum, 32);
      lq = lq * corr + sum;
      // O^T rescale: column q = l16 -> lane-local corr, no shuffle
#pragma unroll
      for (int nt = 0; nt < 4; ++nt)
#pragma unroll
        for (int r = 0; r < 4; ++r) o[nt][r] *= corr;

      // P^T -> wave-private LDS as [q][key] (same-wave RAW, lgkm-tracked)
      __bf16* pw = &Pl[wave][0];
#pragma unroll
      for (int jj = 0; jj < 4; ++jj)
#pragma unroll
        for (int r = 0; r < 4; ++r)
          pw[l16 * ALDP + jj * 16 + quad * 4 + r] = (__bf16)sc[jj][r];

      // O^T += V^T·P^T : A = V^T-frag (m=d), B = P-frag (n=q)
#pragma unroll
      for (int s = 0; s < 2; ++s) {
        bf16_8 pf = *(const bf16_8*)(&pw[l16 * ALDP + s * 32 + quad * 8]);
#pragma unroll
        for (int dt = 0; dt < 4; ++dt) {
          bf16_8 vf = *(const bf16_8*)(&Vt[(dt * 16 + l16) * ALDP + s * 32 + quad * 8]);
          o[dt] = __builtin_amdgcn_mfma_f32_16x16x32_bf16(vf, pf, o[dt], 0, 0, 0);
        }
      }
    }

    // epilogue: normalize (lane-local 1/lq), transpose via Pl, coalesced store
    const float inv = 1.f / lq;
    __bf16* pw = &Pl[wave][0];
#pragma unroll
    for (int dt = 0; dt < 4; ++dt)
#pragma unroll
      for (int r = 0; r < 4; ++r)
        pw[l16 * ALDP + dt * 16 + quad * 4 + r] = (__bf16)(o[dt][r] * inv);
#pragma unroll
    for (int u = 0; u < 2; ++u) {
      int j = lane + u * 64;          // 0..127
      int ql = j >> 3, ch = j & 7;    // query-local 0..15, 8-elem chunk 0..7
      bf16_8 ov = *(const bf16_8*)(&pw[ql * ALDP + ch * 8]);
      *(bf16_8*)(ob + base + (size_t)(qw + ql) * E + ch * 8) = ov;
    }
  }
}

// ---------------------------------------------------------------- launch
extern "C" void kernel_launch(void* const* d_in, const int* in_sizes, int n_in,
                              void* d_out, int out_size, void* d_ws, size_t ws_size,
                              hipStream_t stream) {
  const int Bv = 2, S = 2048, E = 768, FF = 3072;
  const int M = Bv * S;  // 4096
  const size_t ME = (size_t)M * E;       // 3145728 elems / slot
  const size_t EE = (size_t)E * E;       // 589824
  const size_t EF = (size_t)E * FF;      // 2359296

  const float* x = (const float*)d_in[0];
  const float* wq = (const float*)d_in[1];
  const float* wk = (const float*)d_in[2];
  const float* wv = (const float*)d_in[3];
  const float* wo = (const float*)d_in[4];
  const float* bo = (const float*)d_in[5];
  const float* w1 = (const float*)d_in[6];
  const float* b1 = (const float*)d_in[7];
  const float* w2 = (const float*)d_in[8];
  const float* b2 = (const float*)d_in[9];
  const float* gamma = (const float*)d_in[10];
  const float* beta = (const float*)d_in[11];

  // ws: [ctr + pad 256B][5 slots of M*E bf16] = 31.46 MB total (unchanged footprint).
  // s0: xn -> attn -> y       s1..s3: q,k,v       s1..s2: h-half (FFN split in two)
  // s4: {wq,wk,wv,wo} bf16 (4*EE = 2359296 <= ME), later w2 bf16 (EF <= ME)
  // s3: later w1 bf16 (EF <= ME).   res (fp32) lives in d_out, seeded by async copy of x.
  int* ctr = (int*)d_ws;
  __hip_bfloat16* slot = (__hip_bfloat16*)((char*)d_ws + 256);
  __hip_bfloat16* s0 = slot;
  __hip_bfloat16* s1 = slot + ME;
  __hip_bfloat16* s2 = slot + 2 * ME;
  __hip_bfloat16* s3 = slot + 3 * ME;
  __hip_bfloat16* s4 = slot + 4 * ME;
  float* res = (float*)d_out;

  // 0. convert attention weights fp32 -> bf16 into s4 (wq|wk|wv|wo contiguous)
  cvt_multi<<<dim3(EE / 1024, 4), 256, 0, stream>>>(
      wq, wk, wv, wo, s4, s4 + EE, s4 + 2 * EE, s4 + 3 * EE);
  // 1. LN1 (x fp32 -> xn bf16 in s0)
  ln_kernel<<<M, 256, 0, stream>>>(x, gamma, beta, s0, E);
  // 2. fused Q/K/V projection: N = 2304 over contiguous wqkv; out -> q,k,v slots s1..s3
  gemm_bt<0><<<dim3(18, 32), 256, 0, stream>>>(s0, s4, nullptr, s1, M, 2304, E, E, E, 0);
  // 3. causal flash attention (persistent, work-stealing) -> s0
  zero_ctr<<<1, 64, 0, stream>>>(ctr);
  attn_mfma<<<768, 256, 0, stream>>>(s1, s2, s3, s0, ctr);
  // 4a. seed residual: res = x (fp32 d2d copy, graph-safe)
  hipMemcpyAsync(d_out, x, ME * sizeof(float), hipMemcpyDeviceToDevice, stream);
  // 4b. attn-proj accumulate: res += attn@wo^T + bo (split-K 2 -> 384 blocks)
  gemm_bt<2><<<dim3(6, 32, 2), 256, 0, stream>>>(s0, s4 + 3 * EE, bo, res, M, E, E, E, E, 0);
  // 4c. convert FFN weights (after proj consumed wo): w1 -> s3, w2 -> s4
  cvt_multi<<<dim3(EF / 1024, 2), 256, 0, stream>>>(
      w1, w2, nullptr, nullptr, s3, s4, nullptr, nullptr);
  // 5. LN2 (res fp32 -> y bf16 in s0)
  ln_kernel<<<M, 256, 0, stream>>>(res, gamma, beta, s0, E);
  // 6+7. FFN in two FF=1536 halves (h-half fits s1..s2; keeps ws at 31.46 MB)
  //   up-a: h = gelu(y @ w1[0:1536]^T + b1[0:1536])  -> s1 [M,1536]
  gemm_bt<1><<<dim3(12, 32), 256, 0, stream>>>(s0, s3, b1, s1, M, 1536, E, E, E, 1536);
  //   down-a: res += h @ w2[:,0:1536]^T + b2          (split-K 2)
  gemm_bt<2><<<dim3(6, 32, 2), 256, 0, stream>>>(s1, s4, b2, res, M, E, 1536, 1536, FF, 0);
  //   up-b: h = gelu(y @ w1[1536:3072]^T + b1[1536:]) -> s1
  gemm_bt<1><<<dim3(12, 32), 256, 0, stream>>>(
      s0, s3 + (size_t)1536 * E, b1 + 1536, s1, M, 1536, E, E, E, 1536);
  //   down-b: res += h @ w2[:,1536:3072]^T            (no bias — already added)
  gemm_bt<2><<<dim3(6, 32, 2), 256, 0, stream>>>(
      s1, s4 + 1536, nullptr, res, M, E, 1536, 1536, FF, 0);
}

// Round 2
// 393.688 us; speedup vs baseline: 1.0316x; 1.0316x over previous
//
#include <hip/hip_runtime.h>
#include <hip/hip_bf16.h>
#include <math.h>

typedef __bf16 bf16_8 __attribute__((ext_vector_type(8)));
typedef __bf16 bf16_4 __attribute__((ext_vector_type(4)));
typedef float f32x4 __attribute__((ext_vector_type(4)));

// ---------------------------------------------------------------- LayerNorm (fp32 in -> bf16 out)
__global__ __launch_bounds__(256) void ln_kernel(
    const float* __restrict__ x, const float* __restrict__ g,
    const float* __restrict__ b, __hip_bfloat16* __restrict__ out, int cols) {
  const int row = blockIdx.x;
  const int t = threadIdx.x;
  float loc[3];
  float s = 0.f, s2 = 0.f;
#pragma unroll
  for (int i = 0; i < 3; ++i) {
    float v = x[(size_t)row * cols + t + i * 256];
    loc[i] = v;
    s += v;
    s2 += v * v;
  }
#pragma unroll
  for (int off = 32; off; off >>= 1) {
    s += __shfl_down(s, off);
    s2 += __shfl_down(s2, off);
  }
  __shared__ float red[2][4];
  const int lane = t & 63, w = t >> 6;
  if (lane == 0) {
    red[0][w] = s;
    red[1][w] = s2;
  }
  __syncthreads();
  s = red[0][0] + red[0][1] + red[0][2] + red[0][3];
  s2 = red[1][0] + red[1][1] + red[1][2] + red[1][3];
  const float mu = s / cols;
  const float var = s2 / cols - mu * mu;
  const float rs = rsqrtf(var + 1e-5f);
  __hip_bfloat16* orow = out + (size_t)row * cols;
#pragma unroll
  for (int i = 0; i < 3; ++i) {
    int c = t + i * 256;
    orow[c] = __hip_bfloat16((loc[i] - mu) * rs * g[c] + b[c]);
  }
}

// ---------------------------------------------------------------- fp32 -> bf16 weight conversion
// grid = (n/1024, nsrc); each of the nsrc matrices has exactly n elements (n % 1024 == 0).
__global__ __launch_bounds__(256) void cvt_multi(
    const float* __restrict__ sa, const float* __restrict__ sb,
    const float* __restrict__ sc, const float* __restrict__ sd,
    __hip_bfloat16* __restrict__ da, __hip_bfloat16* __restrict__ db,
    __hip_bfloat16* __restrict__ dc, __hip_bfloat16* __restrict__ dd) {
  const float* src;
  __hip_bfloat16* dst;
  if (blockIdx.y == 0) { src = sa; dst = da; }
  else if (blockIdx.y == 1) { src = sb; dst = db; }
  else if (blockIdx.y == 2) { src = sc; dst = dc; }
  else { src = sd; dst = dd; }
  const size_t i = ((size_t)blockIdx.x * 256 + threadIdx.x) * 4;
  float4 f = *(const float4*)(src + i);
  bf16_4 o;
  o[0] = (__bf16)f.x; o[1] = (__bf16)f.y; o[2] = (__bf16)f.z; o[3] = (__bf16)f.w;
  *(bf16_4*)((__bf16*)dst + i) = o;
}

// ---------------------------------------------------------------- GEMM: C = A[M,K] @ B[N,K]^T
// m97 structure: 128x128 tile, BK=64, global_load_lds dwordx4 staging, 2-barrier loop.
// A is always bf16 (global_load_lds). B: bf16 via global_load_lds (BF32=false) or
// fp32 reg-staged + convert into padded LDS (BF32=true, conflict-free reads/writes).
// MODE 0 (QKV):  out bf16 split into 3 contiguous [M,768] slots by n/768
// MODE 1 (GELU): out bf16 = gelu_erf(acc + bias[col]), ldout given
// MODE 2 (ACC):  split-K over gridDim.z; atomicAdd fp32 into out[row*768+col]; bias at z==0
template <int MODE, bool BF32>
__global__ __launch_bounds__(256) void gemm_bt(
    const __hip_bfloat16* __restrict__ A, const void* __restrict__ Bx,
    const float* __restrict__ bias, void* __restrict__ out,
    int M, int N, int K, int lda, int ldb, int ldout) {
  constexpr int BM = 128, BN = 128, BK = 64;
  constexpr int LDBP = BF32 ? 72 : BK;  // padded B stride when reg-staged
  __shared__ __align__(16) __bf16 As[BM * BK];
  __shared__ __align__(16) __bf16 Bs[BN * LDBP];
  const int tid = threadIdx.x;
  const int m0 = blockIdx.y * BM;
  const int n0 = blockIdx.x * BN;
  const int wave = tid >> 6;
  const int lane = tid & 63;
  const int quad = lane >> 4;
  const int l16 = lane & 15;
  const int wm = (wave & 1) * 64;
  const int wn = (wave >> 1) * 64;

  int kbase = 0, kcnt = K;
  if constexpr (MODE == 2) {
    kcnt = K / gridDim.z;
    kbase = blockIdx.z * kcnt;
  }

  // global_load_lds staging: each call a wave writes 1 KiB = 8 rows of 64 bf16.
  // LDS dest = wave-uniform base + lane*16; per-lane global src matches that order.
  const int srow = lane >> 3;
  const int scol = (lane & 7) * 8;
  const __hip_bfloat16* Ap = A + (size_t)(m0 + wave * 8 + srow) * lda + kbase + scol;
  const __hip_bfloat16* Bpb = nullptr;
  const float* Bpf = nullptr;
  if constexpr (BF32)
    Bpf = (const float*)Bx;
  else
    Bpb = (const __hip_bfloat16*)Bx + (size_t)(n0 + wave * 8 + srow) * ldb + kbase + scol;

  f32x4 acc[4][4] = {};

  for (int k0 = 0; k0 < kcnt; k0 += BK) {
    __syncthreads();  // previous tile's ds_reads done before overwrite
#pragma unroll
    for (int u = 0; u < 4; ++u) {
      __builtin_amdgcn_global_load_lds(
          (const __attribute__((address_space(1))) void*)(Ap + (size_t)(u * 32) * lda + k0),
          (__attribute__((address_space(3))) void*)(&As[(u * 32 + wave * 8) * BK]), 16, 0, 0);
      if constexpr (!BF32)
        __builtin_amdgcn_global_load_lds(
            (const __attribute__((address_space(1))) void*)(Bpb + (size_t)(u * 32) * ldb + k0),
            (__attribute__((address_space(3))) void*)(&Bs[(u * 32 + wave * 8) * BK]), 16, 0, 0);
    }
    if constexpr (BF32) {
#pragma unroll
      for (int u = 0; u < 4; ++u) {
        int c = u * 256 + tid;          // chunk 0..1023
        int row = c >> 3, kc = c & 7;   // row 0..127, 8-elem k-chunk
        const float* src = Bpf + (size_t)(n0 + row) * ldb + kbase + k0 + kc * 8;
        float4 f0 = *(const float4*)src;
        float4 f1 = *(const float4*)(src + 4);
        bf16_8 bv;
        bv[0] = (__bf16)f0.x; bv[1] = (__bf16)f0.y; bv[2] = (__bf16)f0.z; bv[3] = (__bf16)f0.w;
        bv[4] = (__bf16)f1.x; bv[5] = (__bf16)f1.y; bv[6] = (__bf16)f1.z; bv[7] = (__bf16)f1.w;
        *(bf16_8*)(&Bs[row * LDBP + kc * 8]) = bv;
      }
    }
    __syncthreads();  // compiler emits vmcnt/lgkm drain before this barrier
#pragma unroll
    for (int kk = 0; kk < 2; ++kk) {
      bf16_8 af[4], bfr[4];
#pragma unroll
      for (int i = 0; i < 4; ++i)
        af[i] = *(const bf16_8*)(&As[(wm + i * 16 + l16) * BK + kk * 32 + quad * 8]);
#pragma unroll
      for (int j = 0; j < 4; ++j)
        bfr[j] = *(const bf16_8*)(&Bs[(wn + j * 16 + l16) * LDBP + kk * 32 + quad * 8]);
#pragma unroll
      for (int i = 0; i < 4; ++i)
#pragma unroll
        for (int j = 0; j < 4; ++j)
          acc[i][j] =
              __builtin_amdgcn_mfma_f32_16x16x32_bf16(af[i], bfr[j], acc[i][j], 0, 0, 0);
    }
  }

  // epilogue: C/D layout col = l16, row = quad*4 + r (verified m89/m91)
#pragma unroll
  for (int i = 0; i < 4; ++i) {
#pragma unroll
    for (int j = 0; j < 4; ++j) {
#pragma unroll
      for (int r = 0; r < 4; ++r) {
        const int row = m0 + wm + i * 16 + quad * 4 + r;
        const int col = n0 + wn + j * 16 + l16;
        const float v = acc[i][j][r];
        if constexpr (MODE == 0) {
          const int tsel = n0 / 768;
          const size_t idx = ((size_t)tsel * M + row) * 768 + (col - tsel * 768);
          ((__hip_bfloat16*)out)[idx] = __hip_bfloat16(v);
        } else if constexpr (MODE == 1) {
          float tt = v + bias[col];
          float gl = 0.5f * tt * (1.0f + erff(tt * 0.70710678118654752f));
          ((__hip_bfloat16*)out)[(size_t)row * ldout + col] = __hip_bfloat16(gl);
        } else {
          float add = v + ((blockIdx.z == 0 && bias) ? bias[col] : 0.f);
          atomicAdd((float*)out + (size_t)row * 768 + col, add);
        }
      }
    }
  }
}

// ---------------------------------------------------------------- work counter
__global__ void zero_ctr(int* __restrict__ c) {
  if (threadIdx.x == 0) *c = 0;
}

// ---------------------------------------------------------------- MFMA flash attention (S^T / O^T form)
// Persistent blocks + atomic work-stealing over heavy-first (qblk desc) tasks.
#define ALDP 72
__global__ __launch_bounds__(256) void attn_mfma(
    const __hip_bfloat16* __restrict__ qb, const __hip_bfloat16* __restrict__ kb,
    const __hip_bfloat16* __restrict__ vb, __hip_bfloat16* __restrict__ ob,
    int* __restrict__ ctr) {
  const int S = 2048, H = 12, E = 768;
  const int tid = threadIdx.x;
  const int wave = tid >> 6;
  const int lane = tid & 63;
  const int quad = lane >> 4;
  const int l16 = lane & 15;

  __shared__ __align__(16) __bf16 Ks[64 * ALDP];     // [key][d]
  __shared__ __align__(16) __bf16 Vt[64 * ALDP];     // [d][key]
  __shared__ __align__(16) __bf16 Pl[4][16 * ALDP];  // wave-private [q][*]
  __shared__ int task;

  for (;;) {
    if (tid == 0) task = atomicAdd(ctr, 1);
    __syncthreads();
    const int t = task;
    if (t >= 24 * 32) return;
    const int qblk = 31 - (t / 24);            // heaviest first
    const int bh = t - (t / 24) * 24;
    const int b = bh / H, h = bh - b * H;
    const int q0 = qblk * 64;
    const int qw = q0 + wave * 16;             // wave's first query
    const size_t base = (size_t)b * S * E + (size_t)h * 64;

    // Q fragments (B-operand: n = q = l16, k = d)
    bf16_8 qf[2];
#pragma unroll
    for (int s = 0; s < 2; ++s)
      qf[s] = *(const bf16_8*)(qb + base + (size_t)(qw + l16) * E + s * 32 + quad * 8);

    f32x4 o[4] = {};              // O^T: row d = dt*16+quad*4+r, col q = l16
    float mq = -1e30f, lq = 0.f;  // per-lane stats for query l16

    for (int kt = 0; kt <= qblk; ++kt) {
      const int k0 = kt * 64;
      __syncthreads();
      // stage K (vector b128) and V transposed (scalar)
#pragma unroll
      for (int u = 0; u < 2; ++u) {
        int i = tid + u * 256;
        int kr = i >> 3, kc = i & 7;
        *(bf16_8*)(&Ks[kr * ALDP + kc * 8]) =
            *(const bf16_8*)(kb + base + (size_t)(k0 + kr) * E + kc * 8);
      }
#pragma unroll
      for (int u = 0; u < 2; ++u) {
        int i = tid + u * 256;
        int kr = i & 63, dq = i >> 6;
        bf16_8 vv = *(const bf16_8*)(vb + base + (size_t)(k0 + kr) * E + dq * 8);
#pragma unroll
        for (int j = 0; j < 8; ++j) Vt[(dq * 8 + j) * ALDP + kr] = vv[j];
      }
      __syncthreads();

      // S^T = K·Q^T
      f32x4 sc[4] = {};
#pragma unroll
      for (int jj = 0; jj < 4; ++jj)
#pragma unroll
        for (int s = 0; s < 2; ++s) {
          bf16_8 kf = *(const bf16_8*)(&Ks[(jj * 16 + l16) * ALDP + s * 32 + quad * 8]);
          sc[jj] = __builtin_amdgcn_mfma_f32_16x16x32_bf16(kf, qf[s], sc[jj], 0, 0, 0);
        }

      // scale + causal mask + per-lane max over the 16 (jj,r) key-scores
      float mx = -1e30f;
#pragma unroll
      for (int jj = 0; jj < 4; ++jj)
#pragma unroll
        for (int r = 0; r < 4; ++r) {
          float v = sc[jj][r] * 0.125f;  // 1/sqrt(64)
          if (kt == qblk && (k0 + jj * 16 + quad * 4 + r) > (qw + l16)) v = -1e30f;
          sc[jj][r] = v;
          mx = fmaxf(mx, v);
        }
      mx = fmaxf(mx, __shfl_xor(mx, 16));
      mx = fmaxf(mx, __shfl_xor(mx, 32));
      const float mn = fmaxf(mq, mx);
      const float corr = __expf(mq - mn);
      mq = mn;
      float sum = 0.f;
#pragma unroll
      for (int jj = 0; jj < 4; ++jj)
#pragma unroll
        for (int r = 0; r < 4; ++r) {
          float p = __expf(sc[jj][r] - mn);
          sc[jj][r] = p;
          sum += p;
        }
      sum += __shfl_xor(sum, 16);
      sum += __shfl_xor(sum, 32);
      lq = lq * corr + sum;
      // O^T rescale: column q = l16 -> lane-local corr, no shuffle
#pragma unroll
      for (int nt = 0; nt < 4; ++nt)
#pragma unroll
        for (int r = 0; r < 4; ++r) o[nt][r] *= corr;

      // P^T -> wave-private LDS as [q][key] (same-wave RAW, lgkm-tracked)
      __bf16* pw = &Pl[wave][0];
#pragma unroll
      for (int jj = 0; jj < 4; ++jj)
#pragma unroll
        for (int r = 0; r < 4; ++r)
          pw[l16 * ALDP + jj * 16 + quad * 4 + r] = (__bf16)sc[jj][r];

      // O^T += V^T·P^T : A = V^T-frag (m=d), B = P-frag (n=q)
#pragma unroll
      for (int s = 0; s < 2; ++s) {
        bf16_8 pf = *(const bf16_8*)(&pw[l16 * ALDP + s * 32 + quad * 8]);
#pragma unroll
        for (int dt = 0; dt < 4; ++dt) {
          bf16_8 vf = *(const bf16_8*)(&Vt[(dt * 16 + l16) * ALDP + s * 32 + quad * 8]);
          o[dt] = __builtin_amdgcn_mfma_f32_16x16x32_bf16(vf, pf, o[dt], 0, 0, 0);
        }
      }
    }

    // epilogue: normalize (lane-local 1/lq), transpose via Pl, coalesced store
    const float inv = 1.f / lq;
    __bf16* pw = &Pl[wave][0];
#pragma unroll
    for (int dt = 0; dt < 4; ++dt)
#pragma unroll
      for (int r = 0; r < 4; ++r)
        pw[l16 * ALDP + dt * 16 + quad * 4 + r] = (__bf16)(o[dt][r] * inv);
#pragma unroll
    for (int u = 0; u < 2; ++u) {
      int j = lane + u * 64;          // 0..127
      int ql = j >> 3, ch = j & 7;    // query-local 0..15, 8-elem chunk 0..7
      bf16_8 ov = *(const bf16_8*)(&pw[ql * ALDP + ch * 8]);
      *(bf16_8*)(ob + base + (size_t)(qw + ql) * E + ch * 8) = ov;
    }
  }
}

// ---------------------------------------------------------------- launch
extern "C" void kernel_launch(void* const* d_in, const int* in_sizes, int n_in,
                              void* d_out, int out_size, void* d_ws, size_t ws_size,
                              hipStream_t stream) {
  const int Bv = 2, S = 2048, E = 768, FF = 3072;
  const int M = Bv * S;  // 4096
  const size_t ME = (size_t)M * E;       // 3145728 elems / slot
  const size_t EE = (size_t)E * E;       // 589824
  const size_t EF = (size_t)E * FF;      // 2359296

  const float* x = (const float*)d_in[0];
  const float* wq = (const float*)d_in[1];
  const float* wk = (const float*)d_in[2];
  const float* wv = (const float*)d_in[3];
  const float* wo = (const float*)d_in[4];
  const float* bo = (const float*)d_in[5];
  const float* w1 = (const float*)d_in[6];
  const float* b1 = (const float*)d_in[7];
  const float* w2 = (const float*)d_in[8];
  const float* b2 = (const float*)d_in[9];
  const float* gamma = (const float*)d_in[10];
  const float* beta = (const float*)d_in[11];

  // ws layout: [ctr + pad 256B][5 slots of M*E bf16][optional s5: w1|w2 bf16 (2*EF)]
  // s0: xn -> attn -> y      s1..s3: q,k,v      s1..s4: h (full [M,FF])
  // s4: {wq,wk,wv,wo} bf16 (4*EE <= ME); res (fp32) lives in d_out.
  int* ctr = (int*)d_ws;
  __hip_bfloat16* slot = (__hip_bfloat16*)((char*)d_ws + 256);
  __hip_bfloat16* s0 = slot;
  __hip_bfloat16* s1 = slot + ME;
  __hip_bfloat16* s4 = slot + 4 * ME;
  __hip_bfloat16* s5 = slot + 5 * ME;
  float* res = (float*)d_out;

  const bool big_ws = ws_size >= (size_t)256 + (5 * ME + 2 * EF) * sizeof(__hip_bfloat16);

  // 0. convert attention weights fp32 -> bf16 into s4 (wq|wk|wv|wo contiguous)
  cvt_multi<<<dim3(EE / 1024, 4), 256, 0, stream>>>(
      wq, wk, wv, wo, s4, s4 + EE, s4 + 2 * EE, s4 + 3 * EE);
  if (big_ws)  // FFN weights up front into s5 (w1 | w2)
    cvt_multi<<<dim3(EF / 1024, 2), 256, 0, stream>>>(
        w1, w2, nullptr, nullptr, s5, s5 + EF, nullptr, nullptr);
  // 1. LN1 (x fp32 -> xn bf16 in s0)
  ln_kernel<<<M, 256, 0, stream>>>(x, gamma, beta, s0, E);
  // 2. fused Q/K/V projection: N = 2304 over contiguous wqkv; out -> q,k,v slots s1..s3
  gemm_bt<0, false><<<dim3(18, 32), 256, 0, stream>>>(s0, s4, nullptr, s1, M, 2304, E, E, E, 0);
  // 3. causal flash attention (persistent, work-stealing) -> s0
  zero_ctr<<<1, 64, 0, stream>>>(ctr);
  attn_mfma<<<768, 256, 0, stream>>>(s1, s1 + ME, s1 + 2 * ME, s0, ctr);
  // 4a. seed residual: res = x (fp32 d2d copy, graph-safe)
  hipMemcpyAsync(d_out, x, ME * sizeof(float), hipMemcpyDeviceToDevice, stream);
  // 4b. attn-proj accumulate: res += attn@wo^T + bo (split-K 2 -> 384 blocks)
  gemm_bt<2, false><<<dim3(6, 32, 2), 256, 0, stream>>>(
      s0, s4 + 3 * EE, bo, res, M, E, E, E, E, 0);
  // 5. LN2 (res fp32 -> y bf16 in s0)
  ln_kernel<<<M, 256, 0, stream>>>(res, gamma, beta, s0, E);
  // 6+7. full-FF FFN (768-block grids, 3 blocks/CU)
  if (big_ws) {
    // up: h = gelu(y @ w1^T + b1) -> s1..s4, bf16 weights from s5
    gemm_bt<1, false><<<dim3(24, 32), 256, 0, stream>>>(
        s0, s5, b1, s1, M, FF, E, E, E, FF);
    // down: res += h @ w2^T + b2 (split-K 4 -> 768 blocks)
    gemm_bt<2, false><<<dim3(6, 32, 4), 256, 0, stream>>>(
        s1, s5 + EF, b2, res, M, E, FF, FF, FF, 0);
  } else {
    // up: fp32-w1 reg-staged B (only this GEMM pays the repack)
    gemm_bt<1, true><<<dim3(24, 32), 256, 0, stream>>>(
        s0, w1, b1, s1, M, FF, E, E, E, FF);
    // w2 -> bf16 into s0 (y dead after up)
    cvt_multi<<<dim3(EF / 1024, 1), 256, 0, stream>>>(
        w2, nullptr, nullptr, nullptr, s0, nullptr, nullptr, nullptr);
    // down: res += h @ w2^T + b2 (split-K 4 -> 768 blocks)
    gemm_bt<2, false><<<dim3(6, 32, 4), 256, 0, stream>>>(
        s1, s0, b2, res, M, E, FF, FF, FF, 0);
  }
}

// Round 3
// 333.561 us; speedup vs baseline: 1.2176x; 1.1803x over previous
//
#include <hip/hip_runtime.h>
#include <hip/hip_bf16.h>
#include <math.h>

typedef __bf16 bf16_8 __attribute__((ext_vector_type(8)));
typedef __bf16 bf16_4 __attribute__((ext_vector_type(4)));
typedef float f32x4 __attribute__((ext_vector_type(4)));

#define AS1 __attribute__((address_space(1)))
#define AS3 __attribute__((address_space(3)))

// ---------------------------------------------------------------- LayerNorm (fp32 in -> bf16 out)
__global__ __launch_bounds__(256) void ln_kernel(
    const float* __restrict__ x, const float* __restrict__ g,
    const float* __restrict__ b, __hip_bfloat16* __restrict__ out, int cols) {
  const int row = blockIdx.x;
  const int t = threadIdx.x;
  float loc[3];
  float s = 0.f, s2 = 0.f;
#pragma unroll
  for (int i = 0; i < 3; ++i) {
    float v = x[(size_t)row * cols + t + i * 256];
    loc[i] = v;
    s += v;
    s2 += v * v;
  }
#pragma unroll
  for (int off = 32; off; off >>= 1) {
    s += __shfl_down(s, off);
    s2 += __shfl_down(s2, off);
  }
  __shared__ float red[2][4];
  const int lane = t & 63, w = t >> 6;
  if (lane == 0) {
    red[0][w] = s;
    red[1][w] = s2;
  }
  __syncthreads();
  s = red[0][0] + red[0][1] + red[0][2] + red[0][3];
  s2 = red[1][0] + red[1][1] + red[1][2] + red[1][3];
  const float mu = s / cols;
  const float var = s2 / cols - mu * mu;
  const float rs = rsqrtf(var + 1e-5f);
  __hip_bfloat16* orow = out + (size_t)row * cols;
#pragma unroll
  for (int i = 0; i < 3; ++i) {
    int c = t + i * 256;
    orow[c] = __hip_bfloat16((loc[i] - mu) * rs * g[c] + b[c]);
  }
}

// ---------------------------------------------------------------- fused split-K reduce + residual + LN2
// res[row] = x[row] + sum_z part[z][row] + bias;  y = LN(res) bf16
__global__ __launch_bounds__(256) void reduce_ln(
    const float* __restrict__ x, const float* __restrict__ part, int nz,
    const float* __restrict__ bias, const float* __restrict__ g,
    const float* __restrict__ b, float* __restrict__ res,
    __hip_bfloat16* __restrict__ yout) {
  const int row = blockIdx.x;
  const int t = threadIdx.x;
  const size_t zstride = (size_t)4096 * 768;
  float loc[3];
  float s = 0.f, s2 = 0.f;
#pragma unroll
  for (int i = 0; i < 3; ++i) {
    const int c = t + i * 256;
    const size_t off = (size_t)row * 768 + c;
    float v = x[off] + bias[c];
    for (int z = 0; z < nz; ++z) v += part[(size_t)z * zstride + off];
    res[off] = v;
    loc[i] = v;
    s += v;
    s2 += v * v;
  }
#pragma unroll
  for (int off = 32; off; off >>= 1) {
    s += __shfl_down(s, off);
    s2 += __shfl_down(s2, off);
  }
  __shared__ float red[2][4];
  const int lane = t & 63, w = t >> 6;
  if (lane == 0) {
    red[0][w] = s;
    red[1][w] = s2;
  }
  __syncthreads();
  s = red[0][0] + red[0][1] + red[0][2] + red[0][3];
  s2 = red[1][0] + red[1][1] + red[1][2] + red[1][3];
  const float mu = s / 768.f;
  const float var = s2 / 768.f - mu * mu;
  const float rs = rsqrtf(var + 1e-5f);
#pragma unroll
  for (int i = 0; i < 3; ++i) {
    const int c = t + i * 256;
    yout[(size_t)row * 768 + c] = __hip_bfloat16((loc[i] - mu) * rs * g[c] + b[c]);
  }
}

// ---------------------------------------------------------------- fused split-K reduce into residual (final out)
__global__ __launch_bounds__(256) void reduce_out(
    const float* __restrict__ part, int nz, const float* __restrict__ bias,
    float* __restrict__ res) {
  const int row = blockIdx.x;
  const int t = threadIdx.x;
  const size_t zstride = (size_t)4096 * 768;
#pragma unroll
  for (int i = 0; i < 3; ++i) {
    const int c = t + i * 256;
    const size_t off = (size_t)row * 768 + c;
    float v = res[off] + bias[c];
    for (int z = 0; z < nz; ++z) v += part[(size_t)z * zstride + off];
    res[off] = v;
  }
}

// ---------------------------------------------------------------- fp32 -> bf16 weight conversion
__global__ __launch_bounds__(256) void cvt_multi(
    const float* __restrict__ sa, const float* __restrict__ sb,
    const float* __restrict__ sc, const float* __restrict__ sd,
    __hip_bfloat16* __restrict__ da, __hip_bfloat16* __restrict__ db,
    __hip_bfloat16* __restrict__ dc, __hip_bfloat16* __restrict__ dd) {
  const float* src;
  __hip_bfloat16* dst;
  if (blockIdx.y == 0) { src = sa; dst = da; }
  else if (blockIdx.y == 1) { src = sb; dst = db; }
  else if (blockIdx.y == 2) { src = sc; dst = dc; }
  else { src = sd; dst = dd; }
  const size_t i = ((size_t)blockIdx.x * 256 + threadIdx.x) * 4;
  float4 f = *(const float4*)(src + i);
  bf16_4 o;
  o[0] = (__bf16)f.x; o[1] = (__bf16)f.y; o[2] = (__bf16)f.z; o[3] = (__bf16)f.w;
  *(bf16_4*)((__bf16*)dst + i) = o;
}

// ---------------------------------------------------------------- GEMM: C = A[M,K] @ B[N,K]^T
// 128x128 tile, BK=64, double-buffered LDS, ONE barrier per K-step (T3-minimum),
// global_load_lds dwordx4 staging with pre-swizzled source (T2 both-sides XOR:
// phys k-chunk = logical ^ (row&7); fragment reads hit the 8-way b128 floor).
// MODE 0 (QKV):  out bf16 split into 3 contiguous [M,768] slots by n/768
// MODE 1 (GELU): out bf16 = gelu_erf(acc + bias[col]), ldout given
// MODE 2 (ACC):  split-K, atomicAdd fp32 into out[row*768+col]; bias at z==0 (fallback)
// MODE 3 (PART): split-K, plain store partials out[z][row*768+col] fp32
template <int MODE, bool BF32>
__global__ __launch_bounds__(256) void gemm_bt(
    const __hip_bfloat16* __restrict__ A, const void* __restrict__ Bx,
    const float* __restrict__ bias, void* __restrict__ out,
    int M, int N, int K, int lda, int ldb, int ldout) {
  constexpr int BM = 128, BN = 128, BK = 64;
  constexpr int LDBP = BF32 ? 72 : BK;  // padded B stride when reg-staged fp32
  __shared__ __align__(16) __bf16 As[2][BM * BK];
  __shared__ __align__(16) __bf16 Bs[2][BN * LDBP];
  const int tid = threadIdx.x;
  const int m0 = blockIdx.y * BM;
  const int n0 = blockIdx.x * BN;
  const int wave = tid >> 6;
  const int lane = tid & 63;
  const int quad = lane >> 4;
  const int l16 = lane & 15;
  const int wm = (wave & 1) * 64;
  const int wn = (wave >> 1) * 64;

  int kbase = 0, kcnt = K;
  if constexpr (MODE == 2 || MODE == 3) {
    kcnt = K / gridDim.z;
    kbase = blockIdx.z * kcnt;
  }
  const int nt = kcnt / BK;

  // staging: lane l -> tile-row (l>>3), SWIZZLED source k-chunk ((l&7)^((l>>3)&7)).
  // LDS dest is linear (base + l*16), so LDS phys chunk s holds logical chunk s^(row&7).
  const int srow = lane >> 3;
  const int scol = ((lane & 7) ^ (srow & 7)) * 8;
  const __hip_bfloat16* Ap = A + (size_t)(m0 + wave * 8 + srow) * lda + kbase + scol;
  const __hip_bfloat16* Bpb = nullptr;
  const float* Bpf = nullptr;
  if constexpr (BF32)
    Bpf = (const float*)Bx;
  else
    Bpb = (const __hip_bfloat16*)Bx + (size_t)(n0 + wave * 8 + srow) * ldb + kbase + scol;

  f32x4 acc[4][4] = {};

  auto STAGE = [&](int t, int buf) {
    const int k0 = t * BK;
#pragma unroll
    for (int u = 0; u < 4; ++u) {
      __builtin_amdgcn_global_load_lds(
          (const AS1 void*)(Ap + (size_t)(u * 32) * lda + k0),
          (AS3 void*)(&As[buf][(u * 32 + wave * 8) * BK]), 16, 0, 0);
      if constexpr (!BF32)
        __builtin_amdgcn_global_load_lds(
            (const AS1 void*)(Bpb + (size_t)(u * 32) * ldb + k0),
            (AS3 void*)(&Bs[buf][(u * 32 + wave * 8) * BK]), 16, 0, 0);
    }
    if constexpr (BF32) {
#pragma unroll
      for (int u = 0; u < 4; ++u) {
        int c = u * 256 + tid;
        int row = c >> 3, kc = c & 7;
        const float* src = Bpf + (size_t)(n0 + row) * ldb + kbase + k0 + kc * 8;
        float4 f0 = *(const float4*)src;
        float4 f1 = *(const float4*)(src + 4);
        bf16_8 bv;
        bv[0] = (__bf16)f0.x; bv[1] = (__bf16)f0.y; bv[2] = (__bf16)f0.z; bv[3] = (__bf16)f0.w;
        bv[4] = (__bf16)f1.x; bv[5] = (__bf16)f1.y; bv[6] = (__bf16)f1.z; bv[7] = (__bf16)f1.w;
        *(bf16_8*)(&Bs[buf][row * LDBP + kc * 8]) = bv;
      }
    }
  };

  STAGE(0, 0);
  __syncthreads();  // implicit vmcnt(0): buf0 staged
  int cur = 0;
  for (int t = 0; t < nt; ++t) {
    if (t + 1 < nt) STAGE(t + 1, cur ^ 1);  // prefetch overlaps this tile's compute
#pragma unroll
    for (int kk = 0; kk < 2; ++kk) {
      bf16_8 af[4], bfr[4];
#pragma unroll
      for (int i = 0; i < 4; ++i)
        af[i] = *(const bf16_8*)(
            &As[cur][(wm + i * 16 + l16) * BK + (((kk * 4 + quad) ^ (l16 & 7)) * 8)]);
#pragma unroll
      for (int j = 0; j < 4; ++j) {
        if constexpr (BF32)
          bfr[j] = *(const bf16_8*)(&Bs[cur][(wn + j * 16 + l16) * LDBP + kk * 32 + quad * 8]);
        else
          bfr[j] = *(const bf16_8*)(
              &Bs[cur][(wn + j * 16 + l16) * BK + (((kk * 4 + quad) ^ (l16 & 7)) * 8)]);
      }
#pragma unroll
      for (int i = 0; i < 4; ++i)
#pragma unroll
        for (int j = 0; j < 4; ++j)
          acc[i][j] =
              __builtin_amdgcn_mfma_f32_16x16x32_bf16(af[i], bfr[j], acc[i][j], 0, 0, 0);
    }
    __syncthreads();  // drains vmcnt(0) (prefetch) + all waves done reading buf[cur]
    cur ^= 1;
  }

  // epilogue: C/D layout col = l16, row = quad*4 + r (verified m89/m91)
#pragma unroll
  for (int i = 0; i < 4; ++i) {
#pragma unroll
    for (int j = 0; j < 4; ++j) {
#pragma unroll
      for (int r = 0; r < 4; ++r) {
        const int row = m0 + wm + i * 16 + quad * 4 + r;
        const int col = n0 + wn + j * 16 + l16;
        const float v = acc[i][j][r];
        if constexpr (MODE == 0) {
          const int tsel = n0 / 768;
          const size_t idx = ((size_t)tsel * M + row) * 768 + (col - tsel * 768);
          ((__hip_bfloat16*)out)[idx] = __hip_bfloat16(v);
        } else if constexpr (MODE == 1) {
          float tt = v + bias[col];
          float gl = 0.5f * tt * (1.0f + erff(tt * 0.70710678118654752f));
          ((__hip_bfloat16*)out)[(size_t)row * ldout + col] = __hip_bfloat16(gl);
        } else if constexpr (MODE == 2) {
          float add = v + ((blockIdx.z == 0 && bias) ? bias[col] : 0.f);
          atomicAdd((float*)out + (size_t)row * 768 + col, add);
        } else {
          ((float*)out)[(size_t)blockIdx.z * M * 768 + (size_t)row * 768 + col] = v;
        }
      }
    }
  }
}

// ---------------------------------------------------------------- work counter
__global__ void zero_ctr(int* __restrict__ c) {
  if (threadIdx.x == 0) *c = 0;
}

// ---------------------------------------------------------------- MFMA flash attention (S^T / O^T form)
#define ALDP 72
__global__ __launch_bounds__(256) void attn_mfma(
    const __hip_bfloat16* __restrict__ qb, const __hip_bfloat16* __restrict__ kb,
    const __hip_bfloat16* __restrict__ vb, __hip_bfloat16* __restrict__ ob,
    int* __restrict__ ctr) {
  const int S = 2048, H = 12, E = 768;
  const int tid = threadIdx.x;
  const int wave = tid >> 6;
  const int lane = tid & 63;
  const int quad = lane >> 4;
  const int l16 = lane & 15;

  __shared__ __align__(16) __bf16 Ks[64 * ALDP];     // [key][d]
  __shared__ __align__(16) __bf16 Vt[64 * ALDP];     // [d][key]
  __shared__ __align__(16) __bf16 Pl[4][16 * ALDP];  // wave-private [q][*]
  __shared__ int task;

  for (;;) {
    if (tid == 0) task = atomicAdd(ctr, 1);
    __syncthreads();
    const int t = task;
    if (t >= 24 * 32) return;
    const int qblk = 31 - (t / 24);            // heaviest first
    const int bh = t - (t / 24) * 24;
    const int b = bh / H, h = bh - b * H;
    const int q0 = qblk * 64;
    const int qw = q0 + wave * 16;             // wave's first query
    const size_t base = (size_t)b * S * E + (size_t)h * 64;

    bf16_8 qf[2];
#pragma unroll
    for (int s = 0; s < 2; ++s)
      qf[s] = *(const bf16_8*)(qb + base + (size_t)(qw + l16) * E + s * 32 + quad * 8);

    f32x4 o[4] = {};
    float mq = -1e30f, lq = 0.f;

    for (int kt = 0; kt <= qblk; ++kt) {
      const int k0 = kt * 64;
      __syncthreads();
#pragma unroll
      for (int u = 0; u < 2; ++u) {
        int i = tid + u * 256;
        int kr = i >> 3, kc = i & 7;
        *(bf16_8*)(&Ks[kr * ALDP + kc * 8]) =
            *(const bf16_8*)(kb + base + (size_t)(k0 + kr) * E + kc * 8);
      }
#pragma unroll
      for (int u = 0; u < 2; ++u) {
        int i = tid + u * 256;
        int kr = i & 63, dq = i >> 6;
        bf16_8 vv = *(const bf16_8*)(vb + base + (size_t)(k0 + kr) * E + dq * 8);
#pragma unroll
        for (int j = 0; j < 8; ++j) Vt[(dq * 8 + j) * ALDP + kr] = vv[j];
      }
      __syncthreads();

      f32x4 sc[4] = {};
#pragma unroll
      for (int jj = 0; jj < 4; ++jj)
#pragma unroll
        for (int s = 0; s < 2; ++s) {
          bf16_8 kf = *(const bf16_8*)(&Ks[(jj * 16 + l16) * ALDP + s * 32 + quad * 8]);
          sc[jj] = __builtin_amdgcn_mfma_f32_16x16x32_bf16(kf, qf[s], sc[jj], 0, 0, 0);
        }

      float mx = -1e30f;
#pragma unroll
      for (int jj = 0; jj < 4; ++jj)
#pragma unroll
        for (int r = 0; r < 4; ++r) {
          float v = sc[jj][r] * 0.125f;
          if (kt == qblk && (k0 + jj * 16 + quad * 4 + r) > (qw + l16)) v = -1e30f;
          sc[jj][r] = v;
          mx = fmaxf(mx, v);
        }
      mx = fmaxf(mx, __shfl_xor(mx, 16));
      mx = fmaxf(mx, __shfl_xor(mx, 32));
      const float mn = fmaxf(mq, mx);
      const float corr = __expf(mq - mn);
      mq = mn;
      float sum = 0.f;
#pragma unroll
      for (int jj = 0; jj < 4; ++jj)
#pragma unroll
        for (int r = 0; r < 4; ++r) {
          float p = __expf(sc[jj][r] - mn);
          sc[jj][r] = p;
          sum += p;
        }
      sum += __shfl_xor(sum, 16);
      sum += __shfl_xor(sum, 32);
      lq = lq * corr + sum;
#pragma unroll
      for (int nt2 = 0; nt2 < 4; ++nt2)
#pragma unroll
        for (int r = 0; r < 4; ++r) o[nt2][r] *= corr;

      __bf16* pw = &Pl[wave][0];
#pragma unroll
      for (int jj = 0; jj < 4; ++jj)
#pragma unroll
        for (int r = 0; r < 4; ++r)
          pw[l16 * ALDP + jj * 16 + quad * 4 + r] = (__bf16)sc[jj][r];

#pragma unroll
      for (int s = 0; s < 2; ++s) {
        bf16_8 pf = *(const bf16_8*)(&pw[l16 * ALDP + s * 32 + quad * 8]);
#pragma unroll
        for (int dt = 0; dt < 4; ++dt) {
          bf16_8 vf = *(const bf16_8*)(&Vt[(dt * 16 + l16) * ALDP + s * 32 + quad * 8]);
          o[dt] = __builtin_amdgcn_mfma_f32_16x16x32_bf16(vf, pf, o[dt], 0, 0, 0);
        }
      }
    }

    const float inv = 1.f / lq;
    __bf16* pw = &Pl[wave][0];
#pragma unroll
    for (int dt = 0; dt < 4; ++dt)
#pragma unroll
      for (int r = 0; r < 4; ++r)
        pw[l16 * ALDP + dt * 16 + quad * 4 + r] = (__bf16)(o[dt][r] * inv);
#pragma unroll
    for (int u = 0; u < 2; ++u) {
      int j = lane + u * 64;
      int ql = j >> 3, ch = j & 7;
      bf16_8 ov = *(const bf16_8*)(&pw[ql * ALDP + ch * 8]);
      *(bf16_8*)(ob + base + (size_t)(qw + ql) * E + ch * 8) = ov;
    }
  }
}

// ---------------------------------------------------------------- launch
extern "C" void kernel_launch(void* const* d_in, const int* in_sizes, int n_in,
                              void* d_out, int out_size, void* d_ws, size_t ws_size,
                              hipStream_t stream) {
  const int Bv = 2, S = 2048, E = 768, FF = 3072;
  const int M = Bv * S;  // 4096
  const size_t ME = (size_t)M * E;       // 3145728
  const size_t EE = (size_t)E * E;       // 589824
  const size_t EF = (size_t)E * FF;      // 2359296

  const float* x = (const float*)d_in[0];
  const float* wq = (const float*)d_in[1];
  const float* wk = (const float*)d_in[2];
  const float* wv = (const float*)d_in[3];
  const float* wo = (const float*)d_in[4];
  const float* bo = (const float*)d_in[5];
  const float* w1 = (const float*)d_in[6];
  const float* b1 = (const float*)d_in[7];
  const float* w2 = (const float*)d_in[8];
  const float* b2 = (const float*)d_in[9];
  const float* gamma = (const float*)d_in[10];
  const float* beta = (const float*)d_in[11];

  // ws layout: [ctr + 256B][s0..s4: 5×ME bf16][s5: w1|w2 bf16 2×EF][pp: 4×ME fp32 partials]
  int* ctr = (int*)d_ws;
  __hip_bfloat16* slot = (__hip_bfloat16*)((char*)d_ws + 256);
  __hip_bfloat16* s0 = slot;
  __hip_bfloat16* s1 = slot + ME;
  __hip_bfloat16* s4 = slot + 4 * ME;
  __hip_bfloat16* s5 = slot + 5 * ME;
  float* pp = (float*)(slot + 5 * ME + 2 * EF);
  float* res = (float*)d_out;

  const size_t need_mid = 256 + (5 * ME + 2 * EF) * sizeof(__hip_bfloat16);
  const size_t need_full = need_mid + 4 * ME * sizeof(float);
  const bool full = ws_size >= need_full;
  const bool mid = ws_size >= need_mid;

  // 0. weights -> bf16
  cvt_multi<<<dim3(EE / 1024, 4), 256, 0, stream>>>(
      wq, wk, wv, wo, s4, s4 + EE, s4 + 2 * EE, s4 + 3 * EE);
  if (mid)
    cvt_multi<<<dim3(EF / 1024, 2), 256, 0, stream>>>(
        w1, w2, nullptr, nullptr, s5, s5 + EF, nullptr, nullptr);
  // 1. LN1
  ln_kernel<<<M, 256, 0, stream>>>(x, gamma, beta, s0, E);
  // 2. fused Q/K/V projection
  gemm_bt<0, false><<<dim3(18, 32), 256, 0, stream>>>(s0, s4, nullptr, s1, M, 2304, E, E, E, 0);
  // 3. causal flash attention -> s0
  zero_ctr<<<1, 64, 0, stream>>>(ctr);
  attn_mfma<<<768, 256, 0, stream>>>(s1, s1 + ME, s1 + 2 * ME, s0, ctr);

  if (full) {
    // 4. attn-proj: partials z=4 (768 blocks, 3 K-iters each)
    gemm_bt<3, false><<<dim3(6, 32, 4), 256, 0, stream>>>(
        s0, s4 + 3 * EE, nullptr, pp, M, E, E, E, E, 0);
    // 5. res = x + Σpp + bo; y = LN2(res) -> s0   (replaces memcpy + atomics + LN)
    reduce_ln<<<M, 256, 0, stream>>>(x, pp, 4, bo, gamma, beta, res, s0);
    // 6. FFN up + GELU -> s1..s4
    gemm_bt<1, false><<<dim3(24, 32), 256, 0, stream>>>(s0, s5, b1, s1, M, FF, E, E, E, FF);
    // 7. FFN down: partials z=4 (768 blocks, 12 K-iters each)
    gemm_bt<3, false><<<dim3(6, 32, 4), 256, 0, stream>>>(
        s1, s5 + EF, nullptr, pp, M, E, FF, FF, FF, 0);
    // 8. out = res + Σpp + b2
    reduce_out<<<M, 256, 0, stream>>>(pp, 4, b2, res);
  } else {
    // fallback: atomic split-K accumulate paths (round-2 behavior)
    hipMemcpyAsync(d_out, x, ME * sizeof(float), hipMemcpyDeviceToDevice, stream);
    gemm_bt<2, false><<<dim3(6, 32, 2), 256, 0, stream>>>(
        s0, s4 + 3 * EE, bo, res, M, E, E, E, E, 0);
    ln_kernel<<<M, 256, 0, stream>>>(res, gamma, beta, s0, E);
    if (mid) {
      gemm_bt<1, false><<<dim3(24, 32), 256, 0, stream>>>(s0, s5, b1, s1, M, FF, E, E, E, FF);
      gemm_bt<2, false><<<dim3(6, 32, 4), 256, 0, stream>>>(
          s1, s5 + EF, b2, res, M, E, FF, FF, FF, 0);
    } else {
      gemm_bt<1, true><<<dim3(24, 32), 256, 0, stream>>>(s0, w1, b1, s1, M, FF, E, E, E, FF);
      cvt_multi<<<dim3(EF / 1024, 1), 256, 0, stream>>>(
          w2, nullptr, nullptr, nullptr, s0, nullptr, nullptr, nullptr);
      gemm_bt<2, false><<<dim3(6, 32, 4), 256, 0, stream>>>(
          s1, s0, b2, res, M, E, FF, FF, FF, 0);
    }
  }
}

// Round 4
// 332.755 us; speedup vs baseline: 1.2206x; 1.0024x over previous
//
#include <hip/hip_runtime.h>
#include <hip/hip_bf16.h>
#include <math.h>

typedef __bf16 bf16_8 __attribute__((ext_vector_type(8)));
typedef __bf16 bf16_4 __attribute__((ext_vector_type(4)));
typedef float f32x4 __attribute__((ext_vector_type(4)));

#define AS1 __attribute__((address_space(1)))
#define AS3 __attribute__((address_space(3)))

// ---------------------------------------------------------------- LayerNorm (fp32 in -> bf16 out)
__global__ __launch_bounds__(256) void ln_kernel(
    const float* __restrict__ x, const float* __restrict__ g,
    const float* __restrict__ b, __hip_bfloat16* __restrict__ out, int cols) {
  const int row = blockIdx.x;
  const int t = threadIdx.x;
  float loc[3];
  float s = 0.f, s2 = 0.f;
#pragma unroll
  for (int i = 0; i < 3; ++i) {
    float v = x[(size_t)row * cols + t + i * 256];
    loc[i] = v;
    s += v;
    s2 += v * v;
  }
#pragma unroll
  for (int off = 32; off; off >>= 1) {
    s += __shfl_down(s, off);
    s2 += __shfl_down(s2, off);
  }
  __shared__ float red[2][4];
  const int lane = t & 63, w = t >> 6;
  if (lane == 0) {
    red[0][w] = s;
    red[1][w] = s2;
  }
  __syncthreads();
  s = red[0][0] + red[0][1] + red[0][2] + red[0][3];
  s2 = red[1][0] + red[1][1] + red[1][2] + red[1][3];
  const float mu = s / cols;
  const float var = s2 / cols - mu * mu;
  const float rs = rsqrtf(var + 1e-5f);
  __hip_bfloat16* orow = out + (size_t)row * cols;
#pragma unroll
  for (int i = 0; i < 3; ++i) {
    int c = t + i * 256;
    orow[c] = __hip_bfloat16((loc[i] - mu) * rs * g[c] + b[c]);
  }
}

// ---------------------------------------------------------------- fused split-K reduce + residual + LN2
__global__ __launch_bounds__(256) void reduce_ln(
    const float* __restrict__ x, const float* __restrict__ part, int nz,
    const float* __restrict__ bias, const float* __restrict__ g,
    const float* __restrict__ b, float* __restrict__ res,
    __hip_bfloat16* __restrict__ yout) {
  const int row = blockIdx.x;
  const int t = threadIdx.x;
  const size_t zstride = (size_t)4096 * 768;
  float loc[3];
  float s = 0.f, s2 = 0.f;
#pragma unroll
  for (int i = 0; i < 3; ++i) {
    const int c = t + i * 256;
    const size_t off = (size_t)row * 768 + c;
    float v = x[off] + bias[c];
    for (int z = 0; z < nz; ++z) v += part[(size_t)z * zstride + off];
    res[off] = v;
    loc[i] = v;
    s += v;
    s2 += v * v;
  }
#pragma unroll
  for (int off = 32; off; off >>= 1) {
    s += __shfl_down(s, off);
    s2 += __shfl_down(s2, off);
  }
  __shared__ float red[2][4];
  const int lane = t & 63, w = t >> 6;
  if (lane == 0) {
    red[0][w] = s;
    red[1][w] = s2;
  }
  __syncthreads();
  s = red[0][0] + red[0][1] + red[0][2] + red[0][3];
  s2 = red[1][0] + red[1][1] + red[1][2] + red[1][3];
  const float mu = s / 768.f;
  const float var = s2 / 768.f - mu * mu;
  const float rs = rsqrtf(var + 1e-5f);
#pragma unroll
  for (int i = 0; i < 3; ++i) {
    const int c = t + i * 256;
    yout[(size_t)row * 768 + c] = __hip_bfloat16((loc[i] - mu) * rs * g[c] + b[c]);
  }
}

// ---------------------------------------------------------------- fused split-K reduce into residual (final out)
__global__ __launch_bounds__(256) void reduce_out(
    const float* __restrict__ part, int nz, const float* __restrict__ bias,
    float* __restrict__ res) {
  const int row = blockIdx.x;
  const int t = threadIdx.x;
  const size_t zstride = (size_t)4096 * 768;
#pragma unroll
  for (int i = 0; i < 3; ++i) {
    const int c = t + i * 256;
    const size_t off = (size_t)row * 768 + c;
    float v = res[off] + bias[c];
    for (int z = 0; z < nz; ++z) v += part[(size_t)z * zstride + off];
    res[off] = v;
  }
}

// ---------------------------------------------------------------- fp32 -> bf16 weight conversion
__global__ __launch_bounds__(256) void cvt_multi(
    const float* __restrict__ sa, const float* __restrict__ sb,
    const float* __restrict__ sc, const float* __restrict__ sd,
    __hip_bfloat16* __restrict__ da, __hip_bfloat16* __restrict__ db,
    __hip_bfloat16* __restrict__ dc, __hip_bfloat16* __restrict__ dd) {
  const float* src;
  __hip_bfloat16* dst;
  if (blockIdx.y == 0) { src = sa; dst = da; }
  else if (blockIdx.y == 1) { src = sb; dst = db; }
  else if (blockIdx.y == 2) { src = sc; dst = dc; }
  else { src = sd; dst = dd; }
  const size_t i = ((size_t)blockIdx.x * 256 + threadIdx.x) * 4;
  float4 f = *(const float4*)(src + i);
  bf16_4 o;
  o[0] = (__bf16)f.x; o[1] = (__bf16)f.y; o[2] = (__bf16)f.z; o[3] = (__bf16)f.w;
  *(bf16_4*)((__bf16*)dst + i) = o;
}

// ---------------------------------------------------------------- V pre-transpose: vt[bh][d][s] = v[b][s][h*64+d]
// LDS-tiled 64x64; runs once (~19 MB traffic). Enables vector V^T staging in attention.
__global__ __launch_bounds__(256) void transpose_v(
    const __hip_bfloat16* __restrict__ v, __hip_bfloat16* __restrict__ vt) {
  const int S = 2048, E = 768, H = 12;
  const int s0 = blockIdx.x * 64;
  const int bh = blockIdx.y;
  const int b = bh / H, h = bh - b * H;
  __shared__ __align__(16) __bf16 T[64 * 72];
  const int tid = threadIdx.x;
#pragma unroll
  for (int u = 0; u < 2; ++u) {
    int i = tid + u * 256;
    int sr = i >> 3, c = i & 7;
    *(bf16_8*)(&T[sr * 72 + c * 8]) =
        *(const bf16_8*)(v + ((size_t)b * S + s0 + sr) * E + h * 64 + c * 8);
  }
  __syncthreads();
#pragma unroll
  for (int u = 0; u < 2; ++u) {
    int i = tid + u * 256;
    int dr = i >> 3, kc = i & 7;
    bf16_8 o;
#pragma unroll
    for (int e = 0; e < 8; ++e) o[e] = T[(kc * 8 + e) * 72 + dr];
    *(bf16_8*)(vt + ((size_t)bh * 64 + dr) * S + s0 + kc * 8) = o;
  }
}

// ---------------------------------------------------------------- GEMM: C = A[M,K] @ B[N,K]^T
// 128x128 tile, BK=64, double-buffered LDS, ONE barrier per K-step, T2 XOR-swizzled
// global_load_lds staging (unchanged from round 3 — verified working).
template <int MODE, bool BF32>
__global__ __launch_bounds__(256) void gemm_bt(
    const __hip_bfloat16* __restrict__ A, const void* __restrict__ Bx,
    const float* __restrict__ bias, void* __restrict__ out,
    int M, int N, int K, int lda, int ldb, int ldout) {
  constexpr int BM = 128, BN = 128, BK = 64;
  constexpr int LDBP = BF32 ? 72 : BK;
  __shared__ __align__(16) __bf16 As[2][BM * BK];
  __shared__ __align__(16) __bf16 Bs[2][BN * LDBP];
  const int tid = threadIdx.x;
  const int m0 = blockIdx.y * BM;
  const int n0 = blockIdx.x * BN;
  const int wave = tid >> 6;
  const int lane = tid & 63;
  const int quad = lane >> 4;
  const int l16 = lane & 15;
  const int wm = (wave & 1) * 64;
  const int wn = (wave >> 1) * 64;

  int kbase = 0, kcnt = K;
  if constexpr (MODE == 2 || MODE == 3) {
    kcnt = K / gridDim.z;
    kbase = blockIdx.z * kcnt;
  }
  const int nt = kcnt / BK;

  const int srow = lane >> 3;
  const int scol = ((lane & 7) ^ (srow & 7)) * 8;
  const __hip_bfloat16* Ap = A + (size_t)(m0 + wave * 8 + srow) * lda + kbase + scol;
  const __hip_bfloat16* Bpb = nullptr;
  const float* Bpf = nullptr;
  if constexpr (BF32)
    Bpf = (const float*)Bx;
  else
    Bpb = (const __hip_bfloat16*)Bx + (size_t)(n0 + wave * 8 + srow) * ldb + kbase + scol;

  f32x4 acc[4][4] = {};

  auto STAGE = [&](int t, int buf) {
    const int k0 = t * BK;
#pragma unroll
    for (int u = 0; u < 4; ++u) {
      __builtin_amdgcn_global_load_lds(
          (const AS1 void*)(Ap + (size_t)(u * 32) * lda + k0),
          (AS3 void*)(&As[buf][(u * 32 + wave * 8) * BK]), 16, 0, 0);
      if constexpr (!BF32)
        __builtin_amdgcn_global_load_lds(
            (const AS1 void*)(Bpb + (size_t)(u * 32) * ldb + k0),
            (AS3 void*)(&Bs[buf][(u * 32 + wave * 8) * BK]), 16, 0, 0);
    }
    if constexpr (BF32) {
#pragma unroll
      for (int u = 0; u < 4; ++u) {
        int c = u * 256 + tid;
        int row = c >> 3, kc = c & 7;
        const float* src = Bpf + (size_t)(n0 + row) * ldb + kbase + k0 + kc * 8;
        float4 f0 = *(const float4*)src;
        float4 f1 = *(const float4*)(src + 4);
        bf16_8 bv;
        bv[0] = (__bf16)f0.x; bv[1] = (__bf16)f0.y; bv[2] = (__bf16)f0.z; bv[3] = (__bf16)f0.w;
        bv[4] = (__bf16)f1.x; bv[5] = (__bf16)f1.y; bv[6] = (__bf16)f1.z; bv[7] = (__bf16)f1.w;
        *(bf16_8*)(&Bs[buf][row * LDBP + kc * 8]) = bv;
      }
    }
  };

  STAGE(0, 0);
  __syncthreads();
  int cur = 0;
  for (int t = 0; t < nt; ++t) {
    if (t + 1 < nt) STAGE(t + 1, cur ^ 1);
#pragma unroll
    for (int kk = 0; kk < 2; ++kk) {
      bf16_8 af[4], bfr[4];
#pragma unroll
      for (int i = 0; i < 4; ++i)
        af[i] = *(const bf16_8*)(
            &As[cur][(wm + i * 16 + l16) * BK + (((kk * 4 + quad) ^ (l16 & 7)) * 8)]);
#pragma unroll
      for (int j = 0; j < 4; ++j) {
        if constexpr (BF32)
          bfr[j] = *(const bf16_8*)(&Bs[cur][(wn + j * 16 + l16) * LDBP + kk * 32 + quad * 8]);
        else
          bfr[j] = *(const bf16_8*)(
              &Bs[cur][(wn + j * 16 + l16) * BK + (((kk * 4 + quad) ^ (l16 & 7)) * 8)]);
      }
#pragma unroll
      for (int i = 0; i < 4; ++i)
#pragma unroll
        for (int j = 0; j < 4; ++j)
          acc[i][j] =
              __builtin_amdgcn_mfma_f32_16x16x32_bf16(af[i], bfr[j], acc[i][j], 0, 0, 0);
    }
    __syncthreads();
    cur ^= 1;
  }

#pragma unroll
  for (int i = 0; i < 4; ++i) {
#pragma unroll
    for (int j = 0; j < 4; ++j) {
#pragma unroll
      for (int r = 0; r < 4; ++r) {
        const int row = m0 + wm + i * 16 + quad * 4 + r;
        const int col = n0 + wn + j * 16 + l16;
        const float v = acc[i][j][r];
        if constexpr (MODE == 0) {
          const int tsel = n0 / 768;
          const size_t idx = ((size_t)tsel * M + row) * 768 + (col - tsel * 768);
          ((__hip_bfloat16*)out)[idx] = __hip_bfloat16(v);
        } else if constexpr (MODE == 1) {
          float tt = v + bias[col];
          float gl = 0.5f * tt * (1.0f + erff(tt * 0.70710678118654752f));
          ((__hip_bfloat16*)out)[(size_t)row * ldout + col] = __hip_bfloat16(gl);
        } else if constexpr (MODE == 2) {
          float add = v + ((blockIdx.z == 0 && bias) ? bias[col] : 0.f);
          atomicAdd((float*)out + (size_t)row * 768 + col, add);
        } else {
          ((float*)out)[(size_t)blockIdx.z * M * 768 + (size_t)row * 768 + col] = v;
        }
      }
    }
  }
}

// ---------------------------------------------------------------- work counter
__global__ void zero_ctr(int* __restrict__ c) {
  if (threadIdx.x == 0) *c = 0;
}

// ---------------------------------------------------------------- MFMA flash attention (S^T / O^T form), v2
// Double-buffered K/V (ONE barrier/tile), global_load_lds staging with XOR-swizzled
// source, V pre-transposed globally (PRE_T) so V^T stages with vector loads.
#define ALDP 72
template <bool PRE_T>
__global__ __launch_bounds__(256) void attn_mfma(
    const __hip_bfloat16* __restrict__ qb, const __hip_bfloat16* __restrict__ kb,
    const __hip_bfloat16* __restrict__ vb, __hip_bfloat16* __restrict__ ob,
    int* __restrict__ ctr) {
  const int S = 2048, H = 12, E = 768;
  const int tid = threadIdx.x;
  const int wave = tid >> 6;
  const int lane = tid & 63;
  const int quad = lane >> 4;
  const int l16 = lane & 15;

  __shared__ __align__(16) __bf16 Ks[2][64 * 64];    // [key][d], chunk-XOR swizzled
  __shared__ __align__(16) __bf16 Vt[2][64 * 64];    // [d][key], chunk-XOR swizzled
  __shared__ __align__(16) __bf16 Pl[4][16 * ALDP];  // wave-private [q][key]
  __shared__ int task;

  const int srow8 = lane >> 3;                 // 0..7
  const int csrc = ((lane & 7) ^ srow8) * 8;   // pre-swizzled source k-chunk

  for (;;) {
    if (tid == 0) task = atomicAdd(ctr, 1);
    __syncthreads();
    const int t = task;
    if (t >= 24 * 32) return;
    const int qblk = 31 - (t / 24);            // heaviest first
    const int bh = t - (t / 24) * 24;
    const int b = bh / H, h = bh - b * H;
    const int q0 = qblk * 64;
    const int qw = q0 + wave * 16;
    const size_t base = (size_t)b * S * E + (size_t)h * 64;

    // stage one 64-key tile: K rows (and V^T d-rows if PRE_T) via global_load_lds,
    // linear LDS dest + pre-swizzled source => phys chunk p holds logical p^(row&7).
    auto STAGE = [&](int kts, int buf) {
      const int k0s = kts * 64;
#pragma unroll
      for (int u = 0; u < 2; ++u) {
        const int trow = wave * 16 + u * 8;
        __builtin_amdgcn_global_load_lds(
            (const AS1 void*)(kb + base + (size_t)(k0s + trow + srow8) * E + csrc),
            (AS3 void*)(&Ks[buf][trow * 64]), 16, 0, 0);
        if constexpr (PRE_T)
          __builtin_amdgcn_global_load_lds(
              (const AS1 void*)(vb + ((size_t)(bh * 64 + trow + srow8)) * S + k0s + csrc),
              (AS3 void*)(&Vt[buf][trow * 64]), 16, 0, 0);
      }
      if constexpr (!PRE_T) {
#pragma unroll
        for (int u = 0; u < 2; ++u) {
          int i = tid + u * 256;
          int kr = i & 63, dq = i >> 6;
          bf16_8 vv = *(const bf16_8*)(vb + base + (size_t)(k0s + kr) * E + dq * 8);
#pragma unroll
          for (int j = 0; j < 8; ++j) {
            int drow = dq * 8 + j;
            Vt[buf][drow * 64 + (((kr >> 3) ^ (drow & 7)) * 8) + (kr & 7)] = vv[j];
          }
        }
      }
    };

    // Q fragments (B-operand: n = q = l16, k = d)
    bf16_8 qf[2];
#pragma unroll
    for (int s = 0; s < 2; ++s)
      qf[s] = *(const bf16_8*)(qb + base + (size_t)(qw + l16) * E + s * 32 + quad * 8);

    f32x4 o[4] = {};
    float mq = -1e30f, lq = 0.f;

    STAGE(0, 0);
    __syncthreads();  // implicit vmcnt(0)+lgkm drain: tile 0 staged
    int cur = 0;

    for (int kt = 0; kt <= qblk; ++kt) {
      const int k0 = kt * 64;
      if (kt < qblk) STAGE(kt + 1, cur ^ 1);  // prefetch hides under compute

      // S^T = K·Q^T  (read logical chunk (s*4+quad) at phys ^(l16&7))
      f32x4 sc[4] = {};
      __builtin_amdgcn_s_setprio(1);
#pragma unroll
      for (int jj = 0; jj < 4; ++jj)
#pragma unroll
        for (int s = 0; s < 2; ++s) {
          bf16_8 kf = *(const bf16_8*)(
              &Ks[cur][(jj * 16 + l16) * 64 + (((s * 4 + quad) ^ (l16 & 7)) * 8)]);
          sc[jj] = __builtin_amdgcn_mfma_f32_16x16x32_bf16(kf, qf[s], sc[jj], 0, 0, 0);
        }
      __builtin_amdgcn_s_setprio(0);

      float mx = -1e30f;
#pragma unroll
      for (int jj = 0; jj < 4; ++jj)
#pragma unroll
        for (int r = 0; r < 4; ++r) {
          float v = sc[jj][r] * 0.125f;  // 1/sqrt(64)
          if (kt == qblk && (k0 + jj * 16 + quad * 4 + r) > (qw + l16)) v = -1e30f;
          sc[jj][r] = v;
          mx = fmaxf(mx, v);
        }
      mx = fmaxf(mx, __shfl_xor(mx, 16));
      mx = fmaxf(mx, __shfl_xor(mx, 32));
      const float mn = fmaxf(mq, mx);
      const float corr = __expf(mq - mn);
      mq = mn;
      float sum = 0.f;
#pragma unroll
      for (int jj = 0; jj < 4; ++jj)
#pragma unroll
        for (int r = 0; r < 4; ++r) {
          float p = __expf(sc[jj][r] - mn);
          sc[jj][r] = p;
          sum += p;
        }
      sum += __shfl_xor(sum, 16);
      sum += __shfl_xor(sum, 32);
      lq = lq * corr + sum;
#pragma unroll
      for (int nt2 = 0; nt2 < 4; ++nt2)
#pragma unroll
        for (int r = 0; r < 4; ++r) o[nt2][r] *= corr;

      // P^T -> wave-private LDS, packed b64 (4 consecutive key-slots per write)
      __bf16* pw = &Pl[wave][0];
#pragma unroll
      for (int jj = 0; jj < 4; ++jj) {
        bf16_4 p4;
#pragma unroll
        for (int r = 0; r < 4; ++r) p4[r] = (__bf16)sc[jj][r];
        *(bf16_4*)(&pw[l16 * ALDP + jj * 16 + quad * 4]) = p4;
      }

      // O^T += V^T·P^T
#pragma unroll
      for (int s = 0; s < 2; ++s) {
        bf16_8 pf = *(const bf16_8*)(&pw[l16 * ALDP + s * 32 + quad * 8]);
        __builtin_amdgcn_s_setprio(1);
#pragma unroll
        for (int dt = 0; dt < 4; ++dt) {
          bf16_8 vf = *(const bf16_8*)(
              &Vt[cur][(dt * 16 + l16) * 64 + (((s * 4 + quad) ^ (l16 & 7)) * 8)]);
          o[dt] = __builtin_amdgcn_mfma_f32_16x16x32_bf16(vf, pf, o[dt], 0, 0, 0);
        }
        __builtin_amdgcn_s_setprio(0);
      }

      __syncthreads();  // all waves done with buf[cur]; prefetch of cur^1 drained
      cur ^= 1;
    }

    // epilogue: normalize (lane-local 1/lq), transpose via Pl, coalesced store
    const float inv = 1.f / lq;
    __bf16* pw = &Pl[wave][0];
#pragma unroll
    for (int dt = 0; dt < 4; ++dt) {
      bf16_4 o4;
#pragma unroll
      for (int r = 0; r < 4; ++r) o4[r] = (__bf16)(o[dt][r] * inv);
      *(bf16_4*)(&pw[l16 * ALDP + dt * 16 + quad * 4]) = o4;
    }
#pragma unroll
    for (int u = 0; u < 2; ++u) {
      int j = lane + u * 64;
      int ql = j >> 3, ch = j & 7;
      bf16_8 ov = *(const bf16_8*)(&pw[ql * ALDP + ch * 8]);
      *(bf16_8*)(ob + base + (size_t)(qw + ql) * E + ch * 8) = ov;
    }
  }
}

// ---------------------------------------------------------------- launch
extern "C" void kernel_launch(void* const* d_in, const int* in_sizes, int n_in,
                              void* d_out, int out_size, void* d_ws, size_t ws_size,
                              hipStream_t stream) {
  const int Bv = 2, S = 2048, E = 768, FF = 3072;
  const int M = Bv * S;  // 4096
  const size_t ME = (size_t)M * E;       // 3145728
  const size_t EE = (size_t)E * E;       // 589824
  const size_t EF = (size_t)E * FF;      // 2359296

  const float* x = (const float*)d_in[0];
  const float* wq = (const float*)d_in[1];
  const float* wk = (const float*)d_in[2];
  const float* wv = (const float*)d_in[3];
  const float* wo = (const float*)d_in[4];
  const float* bo = (const float*)d_in[5];
  const float* w1 = (const float*)d_in[6];
  const float* b1 = (const float*)d_in[7];
  const float* w2 = (const float*)d_in[8];
  const float* b2 = (const float*)d_in[9];
  const float* gamma = (const float*)d_in[10];
  const float* beta = (const float*)d_in[11];

  // ws layout: [ctr + 256B][s0..s4: 5×ME bf16][s5: w1|w2 bf16 2×EF][pp: 4×ME fp32]
  // vt (V^T, ME bf16) time-shares the pp region (attn finishes before partials).
  int* ctr = (int*)d_ws;
  __hip_bfloat16* slot = (__hip_bfloat16*)((char*)d_ws + 256);
  __hip_bfloat16* s0 = slot;
  __hip_bfloat16* s1 = slot + ME;
  __hip_bfloat16* s4 = slot + 4 * ME;
  __hip_bfloat16* s5 = slot + 5 * ME;
  float* pp = (float*)(slot + 5 * ME + 2 * EF);
  __hip_bfloat16* vt = (__hip_bfloat16*)pp;
  float* res = (float*)d_out;

  const size_t need_mid = 256 + (5 * ME + 2 * EF) * sizeof(__hip_bfloat16);
  const size_t need_full = need_mid + 4 * ME * sizeof(float);
  const bool full = ws_size >= need_full;
  const bool mid = ws_size >= need_mid;

  // 0. weights -> bf16
  cvt_multi<<<dim3(EE / 1024, 4), 256, 0, stream>>>(
      wq, wk, wv, wo, s4, s4 + EE, s4 + 2 * EE, s4 + 3 * EE);
  if (mid)
    cvt_multi<<<dim3(EF / 1024, 2), 256, 0, stream>>>(
        w1, w2, nullptr, nullptr, s5, s5 + EF, nullptr, nullptr);
  // 1. LN1
  ln_kernel<<<M, 256, 0, stream>>>(x, gamma, beta, s0, E);
  // 2. fused Q/K/V projection -> s1,s2,s3
  gemm_bt<0, false><<<dim3(18, 32), 256, 0, stream>>>(s0, s4, nullptr, s1, M, 2304, E, E, E, 0);
  // 3. causal flash attention -> s0
  zero_ctr<<<1, 64, 0, stream>>>(ctr);
  if (full) {
    transpose_v<<<dim3(32, 24), 256, 0, stream>>>(s1 + 2 * ME, vt);
    attn_mfma<true><<<768, 256, 0, stream>>>(s1, s1 + ME, vt, s0, ctr);
  } else {
    attn_mfma<false><<<768, 256, 0, stream>>>(s1, s1 + ME, s1 + 2 * ME, s0, ctr);
  }

  if (full) {
    // 4. attn-proj partials z=4
    gemm_bt<3, false><<<dim3(6, 32, 4), 256, 0, stream>>>(
        s0, s4 + 3 * EE, nullptr, pp, M, E, E, E, E, 0);
    // 5. res = x + Σpp + bo; y = LN2(res) -> s0
    reduce_ln<<<M, 256, 0, stream>>>(x, pp, 4, bo, gamma, beta, res, s0);
    // 6. FFN up + GELU -> s1..s4
    gemm_bt<1, false><<<dim3(24, 32), 256, 0, stream>>>(s0, s5, b1, s1, M, FF, E, E, E, FF);
    // 7. FFN down partials z=4
    gemm_bt<3, false><<<dim3(6, 32, 4), 256, 0, stream>>>(
        s1, s5 + EF, nullptr, pp, M, E, FF, FF, FF, 0);
    // 8. out = res + Σpp + b2
    reduce_out<<<M, 256, 0, stream>>>(pp, 4, b2, res);
  } else {
    hipMemcpyAsync(d_out, x, ME * sizeof(float), hipMemcpyDeviceToDevice, stream);
    gemm_bt<2, false><<<dim3(6, 32, 2), 256, 0, stream>>>(
        s0, s4 + 3 * EE, bo, res, M, E, E, E, E, 0);
    ln_kernel<<<M, 256, 0, stream>>>(res, gamma, beta, s0, E);
    if (mid) {
      gemm_bt<1, false><<<dim3(24, 32), 256, 0, stream>>>(s0, s5, b1, s1, M, FF, E, E, E, FF);
      gemm_bt<2, false><<<dim3(6, 32, 4), 256, 0, stream>>>(
          s1, s5 + EF, b2, res, M, E, FF, FF, FF, 0);
    } else {
      gemm_bt<1, true><<<dim3(24, 32), 256, 0, stream>>>(s0, w1, b1, s1, M, FF, E, E, E, FF);
      cvt_multi<<<dim3(EF / 1024, 1), 256, 0, stream>>>(
          w2, nullptr, nullptr, nullptr, s0, nullptr, nullptr, nullptr);
      gemm_bt<2, false><<<dim3(6, 32, 4), 256, 0, stream>>>(
          s1, s0, b2, res, M, E, FF, FF, FF, 0);
    }
  }
}

// Round 5
// 330.849 us; speedup vs baseline: 1.2276x; 1.0058x over previous
//
#include <hip/hip_runtime.h>
#include <hip/hip_bf16.h>
#include <math.h>

typedef __bf16 bf16_8 __attribute__((ext_vector_type(8)));
typedef __bf16 bf16_4 __attribute__((ext_vector_type(4)));
typedef float f32x4 __attribute__((ext_vector_type(4)));

#define AS1 __attribute__((address_space(1)))
#define AS3 __attribute__((address_space(3)))

// ---------------------------------------------------------------- LayerNorm (fp32 in -> bf16 out)
__global__ __launch_bounds__(256) void ln_kernel(
    const float* __restrict__ x, const float* __restrict__ g,
    const float* __restrict__ b, __hip_bfloat16* __restrict__ out, int cols) {
  const int row = blockIdx.x;
  const int t = threadIdx.x;
  float loc[3];
  float s = 0.f, s2 = 0.f;
#pragma unroll
  for (int i = 0; i < 3; ++i) {
    float v = x[(size_t)row * cols + t + i * 256];
    loc[i] = v;
    s += v;
    s2 += v * v;
  }
#pragma unroll
  for (int off = 32; off; off >>= 1) {
    s += __shfl_down(s, off);
    s2 += __shfl_down(s2, off);
  }
  __shared__ float red[2][4];
  const int lane = t & 63, w = t >> 6;
  if (lane == 0) {
    red[0][w] = s;
    red[1][w] = s2;
  }
  __syncthreads();
  s = red[0][0] + red[0][1] + red[0][2] + red[0][3];
  s2 = red[1][0] + red[1][1] + red[1][2] + red[1][3];
  const float mu = s / cols;
  const float var = s2 / cols - mu * mu;
  const float rs = rsqrtf(var + 1e-5f);
  __hip_bfloat16* orow = out + (size_t)row * cols;
#pragma unroll
  for (int i = 0; i < 3; ++i) {
    int c = t + i * 256;
    orow[c] = __hip_bfloat16((loc[i] - mu) * rs * g[c] + b[c]);
  }
}

// ---------------------------------------------------------------- fused split-K reduce + residual + LN2
__global__ __launch_bounds__(256) void reduce_ln(
    const float* __restrict__ x, const float* __restrict__ part, int nz,
    const float* __restrict__ bias, const float* __restrict__ g,
    const float* __restrict__ b, float* __restrict__ res,
    __hip_bfloat16* __restrict__ yout) {
  const int row = blockIdx.x;
  const int t = threadIdx.x;
  const size_t zstride = (size_t)4096 * 768;
  float loc[3];
  float s = 0.f, s2 = 0.f;
#pragma unroll
  for (int i = 0; i < 3; ++i) {
    const int c = t + i * 256;
    const size_t off = (size_t)row * 768 + c;
    float v = x[off] + bias[c];
    for (int z = 0; z < nz; ++z) v += part[(size_t)z * zstride + off];
    res[off] = v;
    loc[i] = v;
    s += v;
    s2 += v * v;
  }
#pragma unroll
  for (int off = 32; off; off >>= 1) {
    s += __shfl_down(s, off);
    s2 += __shfl_down(s2, off);
  }
  __shared__ float red[2][4];
  const int lane = t & 63, w = t >> 6;
  if (lane == 0) {
    red[0][w] = s;
    red[1][w] = s2;
  }
  __syncthreads();
  s = red[0][0] + red[0][1] + red[0][2] + red[0][3];
  s2 = red[1][0] + red[1][1] + red[1][2] + red[1][3];
  const float mu = s / 768.f;
  const float var = s2 / 768.f - mu * mu;
  const float rs = rsqrtf(var + 1e-5f);
#pragma unroll
  for (int i = 0; i < 3; ++i) {
    const int c = t + i * 256;
    yout[(size_t)row * 768 + c] = __hip_bfloat16((loc[i] - mu) * rs * g[c] + b[c]);
  }
}

// ---------------------------------------------------------------- fused split-K reduce into residual (final out)
__global__ __launch_bounds__(256) void reduce_out(
    const float* __restrict__ part, int nz, const float* __restrict__ bias,
    float* __restrict__ res) {
  const int row = blockIdx.x;
  const int t = threadIdx.x;
  const size_t zstride = (size_t)4096 * 768;
#pragma unroll
  for (int i = 0; i < 3; ++i) {
    const int c = t + i * 256;
    const size_t off = (size_t)row * 768 + c;
    float v = res[off] + bias[c];
    for (int z = 0; z < nz; ++z) v += part[(size_t)z * zstride + off];
    res[off] = v;
  }
}

// ---------------------------------------------------------------- fp32 -> bf16 weight conversion
__global__ __launch_bounds__(256) void cvt_multi(
    const float* __restrict__ sa, const float* __restrict__ sb,
    const float* __restrict__ sc, const float* __restrict__ sd,
    __hip_bfloat16* __restrict__ da, __hip_bfloat16* __restrict__ db,
    __hip_bfloat16* __restrict__ dc, __hip_bfloat16* __restrict__ dd) {
  const float* src;
  __hip_bfloat16* dst;
  if (blockIdx.y == 0) { src = sa; dst = da; }
  else if (blockIdx.y == 1) { src = sb; dst = db; }
  else if (blockIdx.y == 2) { src = sc; dst = dc; }
  else { src = sd; dst = dd; }
  const size_t i = ((size_t)blockIdx.x * 256 + threadIdx.x) * 4;
  float4 f = *(const float4*)(src + i);
  bf16_4 o;
  o[0] = (__bf16)f.x; o[1] = (__bf16)f.y; o[2] = (__bf16)f.z; o[3] = (__bf16)f.w;
  *(bf16_4*)((__bf16*)dst + i) = o;
}

// ---------------------------------------------------------------- V pre-transpose + key-permute
// vt[bh][d][c] = v[b][s0 + k(c)][h*64+d] where within each 32-key block
// k(c) = 32*(c>>5) + 16*((c&7)>>2) + 4*((c>>3)&3) + (c&3).
// This bijection makes the PV MFMA B-fragment equal the lane-held softmax C-layout
// fragments (key = 32s + 16*(e>>2) + 4*quad + (e&3) at contraction slot quad*8+e),
// so P never round-trips through LDS.
__global__ __launch_bounds__(256) void transpose_v(
    const __hip_bfloat16* __restrict__ v, __hip_bfloat16* __restrict__ vt) {
  const int S = 2048, E = 768, H = 12;
  const int s0 = blockIdx.x * 64;
  const int bh = blockIdx.y;
  const int b = bh / H, h = bh - b * H;
  __shared__ __align__(16) __bf16 T[64 * 72];
  const int tid = threadIdx.x;
#pragma unroll
  for (int u = 0; u < 2; ++u) {
    int i = tid + u * 256;
    int sr = i >> 3, c = i & 7;
    *(bf16_8*)(&T[sr * 72 + c * 8]) =
        *(const bf16_8*)(v + ((size_t)b * S + s0 + sr) * E + h * 64 + c * 8);
  }
  __syncthreads();
#pragma unroll
  for (int u = 0; u < 2; ++u) {
    int i = tid + u * 256;
    int dr = i >> 3, kc = i & 7;
    bf16_8 o;
#pragma unroll
    for (int e = 0; e < 8; ++e) {
      int k = 32 * (kc >> 2) + 16 * (e >> 2) + 4 * (kc & 3) + (e & 3);
      o[e] = T[k * 72 + dr];
    }
    *(bf16_8*)(vt + ((size_t)bh * 64 + dr) * S + s0 + kc * 8) = o;
  }
}

// ---------------------------------------------------------------- GEMM: C = A[M,K] @ B[N,K]^T
// 128x128 tile, BK=64, double-buffered LDS, ONE barrier per K-step, T2 XOR-swizzled
// global_load_lds staging (frozen since round 3 — verified working).
template <int MODE, bool BF32>
__global__ __launch_bounds__(256) void gemm_bt(
    const __hip_bfloat16* __restrict__ A, const void* __restrict__ Bx,
    const float* __restrict__ bias, void* __restrict__ out,
    int M, int N, int K, int lda, int ldb, int ldout) {
  constexpr int BM = 128, BN = 128, BK = 64;
  constexpr int LDBP = BF32 ? 72 : BK;
  __shared__ __align__(16) __bf16 As[2][BM * BK];
  __shared__ __align__(16) __bf16 Bs[2][BN * LDBP];
  const int tid = threadIdx.x;
  const int m0 = blockIdx.y * BM;
  const int n0 = blockIdx.x * BN;
  const int wave = tid >> 6;
  const int lane = tid & 63;
  const int quad = lane >> 4;
  const int l16 = lane & 15;
  const int wm = (wave & 1) * 64;
  const int wn = (wave >> 1) * 64;

  int kbase = 0, kcnt = K;
  if constexpr (MODE == 2 || MODE == 3) {
    kcnt = K / gridDim.z;
    kbase = blockIdx.z * kcnt;
  }
  const int nt = kcnt / BK;

  const int srow = lane >> 3;
  const int scol = ((lane & 7) ^ (srow & 7)) * 8;
  const __hip_bfloat16* Ap = A + (size_t)(m0 + wave * 8 + srow) * lda + kbase + scol;
  const __hip_bfloat16* Bpb = nullptr;
  const float* Bpf = nullptr;
  if constexpr (BF32)
    Bpf = (const float*)Bx;
  else
    Bpb = (const __hip_bfloat16*)Bx + (size_t)(n0 + wave * 8 + srow) * ldb + kbase + scol;

  f32x4 acc[4][4] = {};

  auto STAGE = [&](int t, int buf) {
    const int k0 = t * BK;
#pragma unroll
    for (int u = 0; u < 4; ++u) {
      __builtin_amdgcn_global_load_lds(
          (const AS1 void*)(Ap + (size_t)(u * 32) * lda + k0),
          (AS3 void*)(&As[buf][(u * 32 + wave * 8) * BK]), 16, 0, 0);
      if constexpr (!BF32)
        __builtin_amdgcn_global_load_lds(
            (const AS1 void*)(Bpb + (size_t)(u * 32) * ldb + k0),
            (AS3 void*)(&Bs[buf][(u * 32 + wave * 8) * BK]), 16, 0, 0);
    }
    if constexpr (BF32) {
#pragma unroll
      for (int u = 0; u < 4; ++u) {
        int c = u * 256 + tid;
        int row = c >> 3, kc = c & 7;
        const float* src = Bpf + (size_t)(n0 + row) * ldb + kbase + k0 + kc * 8;
        float4 f0 = *(const float4*)src;
        float4 f1 = *(const float4*)(src + 4);
        bf16_8 bv;
        bv[0] = (__bf16)f0.x; bv[1] = (__bf16)f0.y; bv[2] = (__bf16)f0.z; bv[3] = (__bf16)f0.w;
        bv[4] = (__bf16)f1.x; bv[5] = (__bf16)f1.y; bv[6] = (__bf16)f1.z; bv[7] = (__bf16)f1.w;
        *(bf16_8*)(&Bs[buf][row * LDBP + kc * 8]) = bv;
      }
    }
  };

  STAGE(0, 0);
  __syncthreads();
  int cur = 0;
  for (int t = 0; t < nt; ++t) {
    if (t + 1 < nt) STAGE(t + 1, cur ^ 1);
#pragma unroll
    for (int kk = 0; kk < 2; ++kk) {
      bf16_8 af[4], bfr[4];
#pragma unroll
      for (int i = 0; i < 4; ++i)
        af[i] = *(const bf16_8*)(
            &As[cur][(wm + i * 16 + l16) * BK + (((kk * 4 + quad) ^ (l16 & 7)) * 8)]);
#pragma unroll
      for (int j = 0; j < 4; ++j) {
        if constexpr (BF32)
          bfr[j] = *(const bf16_8*)(&Bs[cur][(wn + j * 16 + l16) * LDBP + kk * 32 + quad * 8]);
        else
          bfr[j] = *(const bf16_8*)(
              &Bs[cur][(wn + j * 16 + l16) * BK + (((kk * 4 + quad) ^ (l16 & 7)) * 8)]);
      }
#pragma unroll
      for (int i = 0; i < 4; ++i)
#pragma unroll
        for (int j = 0; j < 4; ++j)
          acc[i][j] =
              __builtin_amdgcn_mfma_f32_16x16x32_bf16(af[i], bfr[j], acc[i][j], 0, 0, 0);
    }
    __syncthreads();
    cur ^= 1;
  }

#pragma unroll
  for (int i = 0; i < 4; ++i) {
#pragma unroll
    for (int j = 0; j < 4; ++j) {
#pragma unroll
      for (int r = 0; r < 4; ++r) {
        const int row = m0 + wm + i * 16 + quad * 4 + r;
        const int col = n0 + wn + j * 16 + l16;
        const float v = acc[i][j][r];
        if constexpr (MODE == 0) {
          const int tsel = n0 / 768;
          const size_t idx = ((size_t)tsel * M + row) * 768 + (col - tsel * 768);
          ((__hip_bfloat16*)out)[idx] = __hip_bfloat16(v);
        } else if constexpr (MODE == 1) {
          float tt = v + bias[col];
          float gl = 0.5f * tt * (1.0f + erff(tt * 0.70710678118654752f));
          ((__hip_bfloat16*)out)[(size_t)row * ldout + col] = __hip_bfloat16(gl);
        } else if constexpr (MODE == 2) {
          float add = v + ((blockIdx.z == 0 && bias) ? bias[col] : 0.f);
          atomicAdd((float*)out + (size_t)row * 768 + col, add);
        } else {
          ((float*)out)[(size_t)blockIdx.z * M * 768 + (size_t)row * 768 + col] = v;
        }
      }
    }
  }
}

// ---------------------------------------------------------------- work counter
__global__ void zero_ctr(int* __restrict__ c) {
  if (threadIdx.x == 0) *c = 0;
}

// ---------------------------------------------------------------- MFMA flash attention (S^T / O^T form), v3
// Double-buffered K/V (ONE barrier/tile), global_load_lds staging with XOR-swizzled
// source, V pre-transposed + key-permuted globally (PRE_T) so the PV B-fragment is
// the in-register softmax output directly — NO P round-trip through LDS.
// Softmax in exp2 domain; tree-shaped max/sum reductions.
#define ALDP 72
template <bool PRE_T>
__global__ __launch_bounds__(256) void attn_mfma(
    const __hip_bfloat16* __restrict__ qb, const __hip_bfloat16* __restrict__ kb,
    const __hip_bfloat16* __restrict__ vb, __hip_bfloat16* __restrict__ ob,
    int* __restrict__ ctr) {
  const int S = 2048, H = 12, E = 768;
  const int tid = threadIdx.x;
  const int wave = tid >> 6;
  const int lane = tid & 63;
  const int quad = lane >> 4;
  const int l16 = lane & 15;

  __shared__ __align__(16) __bf16 Ks[2][64 * 64];  // [key][d], chunk-XOR swizzled
  __shared__ __align__(16) __bf16 Vt[2][64 * 64];  // [d][key-permuted], chunk-XOR swizzled
  __shared__ int task;
  // epilogue transpose buffer aliases Ks (free after final tile barrier)
  __bf16* ep = &Ks[0][0] + wave * 16 * ALDP;

  const int srow8 = lane >> 3;                // 0..7
  const int csrc = ((lane & 7) ^ srow8) * 8;  // pre-swizzled source chunk

  const float SCL = 0.18033688011112042f;  // (1/sqrt(64)) * log2(e)

  for (;;) {
    if (tid == 0) task = atomicAdd(ctr, 1);
    __syncthreads();
    const int t = task;
    if (t >= 24 * 32) return;
    const int qblk = 31 - (t / 24);  // heaviest first
    const int bh = t - (t / 24) * 24;
    const int b = bh / H, h = bh - b * H;
    const int q0 = qblk * 64;
    const int qw = q0 + wave * 16;
    const size_t base = (size_t)b * S * E + (size_t)h * 64;

    auto STAGE = [&](int kts, int buf) {
      const int k0s = kts * 64;
#pragma unroll
      for (int u = 0; u < 2; ++u) {
        const int trow = wave * 16 + u * 8;
        __builtin_amdgcn_global_load_lds(
            (const AS1 void*)(kb + base + (size_t)(k0s + trow + srow8) * E + csrc),
            (AS3 void*)(&Ks[buf][trow * 64]), 16, 0, 0);
        if constexpr (PRE_T)
          __builtin_amdgcn_global_load_lds(
              (const AS1 void*)(vb + ((size_t)(bh * 64 + trow + srow8)) * S + k0s + csrc),
              (AS3 void*)(&Vt[buf][trow * 64]), 16, 0, 0);
      }
      if constexpr (!PRE_T) {
#pragma unroll
        for (int u = 0; u < 2; ++u) {
          int i = tid + u * 256;
          int kr = i & 63, dq = i >> 6;
          bf16_8 vv = *(const bf16_8*)(vb + base + (size_t)(k0s + kr) * E + dq * 8);
          // key kr -> permuted col c, then chunk-XOR swizzle
          const int c = 32 * (kr >> 5) + 8 * ((kr >> 2) & 3) + 4 * ((kr >> 4) & 1) + (kr & 3);
#pragma unroll
          for (int j = 0; j < 8; ++j) {
            int drow = dq * 8 + j;
            Vt[buf][drow * 64 + (((c >> 3) ^ (drow & 7)) * 8) + (c & 7)] = vv[j];
          }
        }
      }
    };

    // Q fragments (B-operand: n = q = l16, k = d)
    bf16_8 qf[2];
#pragma unroll
    for (int s = 0; s < 2; ++s)
      qf[s] = *(const bf16_8*)(qb + base + (size_t)(qw + l16) * E + s * 32 + quad * 8);

    f32x4 o[4] = {};
    float mq = -1e30f, lq = 0.f;

    STAGE(0, 0);
    __syncthreads();
    int cur = 0;

    for (int kt = 0; kt <= qblk; ++kt) {
      const int k0 = kt * 64;
      if (kt < qblk) STAGE(kt + 1, cur ^ 1);  // prefetch hides under compute

      // S^T = K·Q^T
      f32x4 sc[4] = {};
      __builtin_amdgcn_s_setprio(1);
#pragma unroll
      for (int jj = 0; jj < 4; ++jj)
#pragma unroll
        for (int s = 0; s < 2; ++s) {
          bf16_8 kf = *(const bf16_8*)(
              &Ks[cur][(jj * 16 + l16) * 64 + (((s * 4 + quad) ^ (l16 & 7)) * 8)]);
          sc[jj] = __builtin_amdgcn_mfma_f32_16x16x32_bf16(kf, qf[s], sc[jj], 0, 0, 0);
        }
      __builtin_amdgcn_s_setprio(0);

      // scale into exp2 domain; causal mask on diagonal tile only
#pragma unroll
      for (int jj = 0; jj < 4; ++jj)
#pragma unroll
        for (int r = 0; r < 4; ++r) sc[jj][r] *= SCL;
      if (kt == qblk) {
#pragma unroll
        for (int jj = 0; jj < 4; ++jj)
#pragma unroll
          for (int r = 0; r < 4; ++r)
            if ((k0 + jj * 16 + quad * 4 + r) > (qw + l16)) sc[jj][r] = -1e30f;
      }
      // tree max (depth 4)
      float mj[4];
#pragma unroll
      for (int jj = 0; jj < 4; ++jj)
        mj[jj] = fmaxf(fmaxf(sc[jj][0], sc[jj][1]), fmaxf(sc[jj][2], sc[jj][3]));
      float mx = fmaxf(fmaxf(mj[0], mj[1]), fmaxf(mj[2], mj[3]));
      mx = fmaxf(mx, __shfl_xor(mx, 16));
      mx = fmaxf(mx, __shfl_xor(mx, 32));
      const float mn = fmaxf(mq, mx);
      const float corr = exp2f(mq - mn);
      mq = mn;
      // exp2 + tree sum
      float sj[4];
#pragma unroll
      for (int jj = 0; jj < 4; ++jj) {
#pragma unroll
        for (int r = 0; r < 4; ++r) sc[jj][r] = exp2f(sc[jj][r] - mn);
        sj[jj] = (sc[jj][0] + sc[jj][1]) + (sc[jj][2] + sc[jj][3]);
      }
      float sum = (sj[0] + sj[1]) + (sj[2] + sj[3]);
      sum += __shfl_xor(sum, 16);
      sum += __shfl_xor(sum, 32);
      lq = lq * corr + sum;
#pragma unroll
      for (int nt2 = 0; nt2 < 4; ++nt2)
#pragma unroll
        for (int r = 0; r < 4; ++r) o[nt2][r] *= corr;

      // P fragments in-register: pf[s][e] = P[q=l16][key=32s+16(e>>2)+4quad+(e&3)]
      bf16_8 pf[2];
#pragma unroll
      for (int s = 0; s < 2; ++s)
#pragma unroll
        for (int r = 0; r < 4; ++r) {
          pf[s][r] = (__bf16)sc[2 * s][r];
          pf[s][4 + r] = (__bf16)sc[2 * s + 1][r];
        }

      // O^T += V^T·P^T  (Vt columns pre-permuted to the same key order)
      __builtin_amdgcn_s_setprio(1);
#pragma unroll
      for (int s = 0; s < 2; ++s)
#pragma unroll
        for (int dt = 0; dt < 4; ++dt) {
          bf16_8 vf = *(const bf16_8*)(
              &Vt[cur][(dt * 16 + l16) * 64 + (((s * 4 + quad) ^ (l16 & 7)) * 8)]);
          o[dt] = __builtin_amdgcn_mfma_f32_16x16x32_bf16(vf, pf[s], o[dt], 0, 0, 0);
        }
      __builtin_amdgcn_s_setprio(0);

      __syncthreads();  // all waves done with buf[cur]; prefetch drained
      cur ^= 1;
    }

    // epilogue: normalize (lane-local 1/lq), transpose via ep (aliases Ks), store
    const float inv = 1.f / lq;
#pragma unroll
    for (int dt = 0; dt < 4; ++dt) {
      bf16_4 o4;
#pragma unroll
      for (int r = 0; r < 4; ++r) o4[r] = (__bf16)(o[dt][r] * inv);
      *(bf16_4*)(&ep[l16 * ALDP + dt * 16 + quad * 4]) = o4;
    }
#pragma unroll
    for (int u = 0; u < 2; ++u) {
      int j = lane + u * 64;
      int ql = j >> 3, ch = j & 7;
      bf16_8 ov = *(const bf16_8*)(&ep[ql * ALDP + ch * 8]);
      *(bf16_8*)(ob + base + (size_t)(qw + ql) * E + ch * 8) = ov;
    }
  }
}

// ---------------------------------------------------------------- launch
extern "C" void kernel_launch(void* const* d_in, const int* in_sizes, int n_in,
                              void* d_out, int out_size, void* d_ws, size_t ws_size,
                              hipStream_t stream) {
  const int Bv = 2, S = 2048, E = 768, FF = 3072;
  const int M = Bv * S;  // 4096
  const size_t ME = (size_t)M * E;
  const size_t EE = (size_t)E * E;
  const size_t EF = (size_t)E * FF;

  const float* x = (const float*)d_in[0];
  const float* wq = (const float*)d_in[1];
  const float* wk = (const float*)d_in[2];
  const float* wv = (const float*)d_in[3];
  const float* wo = (const float*)d_in[4];
  const float* bo = (const float*)d_in[5];
  const float* w1 = (const float*)d_in[6];
  const float* b1 = (const float*)d_in[7];
  const float* w2 = (const float*)d_in[8];
  const float* b2 = (const float*)d_in[9];
  const float* gamma = (const float*)d_in[10];
  const float* beta = (const float*)d_in[11];

  // ws layout: [ctr + 256B][s0..s4: 5×ME bf16][s5: w1|w2 bf16 2×EF][pp: 4×ME fp32]
  // vt (V^T, ME bf16) time-shares the pp region (attn finishes before partials).
  int* ctr = (int*)d_ws;
  __hip_bfloat16* slot = (__hip_bfloat16*)((char*)d_ws + 256);
  __hip_bfloat16* s0 = slot;
  __hip_bfloat16* s1 = slot + ME;
  __hip_bfloat16* s4 = slot + 4 * ME;
  __hip_bfloat16* s5 = slot + 5 * ME;
  float* pp = (float*)(slot + 5 * ME + 2 * EF);
  __hip_bfloat16* vt = (__hip_bfloat16*)pp;
  float* res = (float*)d_out;

  const size_t need_mid = 256 + (5 * ME + 2 * EF) * sizeof(__hip_bfloat16);
  const size_t need_full = need_mid + 4 * ME * sizeof(float);
  const bool full = ws_size >= need_full;
  const bool mid = ws_size >= need_mid;

  // 0. weights -> bf16
  cvt_multi<<<dim3(EE / 1024, 4), 256, 0, stream>>>(
      wq, wk, wv, wo, s4, s4 + EE, s4 + 2 * EE, s4 + 3 * EE);
  if (mid)
    cvt_multi<<<dim3(EF / 1024, 2), 256, 0, stream>>>(
        w1, w2, nullptr, nullptr, s5, s5 + EF, nullptr, nullptr);
  // 1. LN1
  ln_kernel<<<M, 256, 0, stream>>>(x, gamma, beta, s0, E);
  // 2. fused Q/K/V projection -> s1,s2,s3
  gemm_bt<0, false><<<dim3(18, 32), 256, 0, stream>>>(s0, s4, nullptr, s1, M, 2304, E, E, E, 0);
  // 3. causal flash attention -> s0
  zero_ctr<<<1, 64, 0, stream>>>(ctr);
  if (full) {
    transpose_v<<<dim3(32, 24), 256, 0, stream>>>(s1 + 2 * ME, vt);
    attn_mfma<true><<<768, 256, 0, stream>>>(s1, s1 + ME, vt, s0, ctr);
  } else {
    attn_mfma<false><<<768, 256, 0, stream>>>(s1, s1 + ME, s1 + 2 * ME, s0, ctr);
  }

  if (full) {
    // 4. attn-proj partials z=4
    gemm_bt<3, false><<<dim3(6, 32, 4), 256, 0, stream>>>(
        s0, s4 + 3 * EE, nullptr, pp, M, E, E, E, E, 0);
    // 5. res = x + Σpp + bo; y = LN2(res) -> s0
    reduce_ln<<<M, 256, 0, stream>>>(x, pp, 4, bo, gamma, beta, res, s0);
    // 6. FFN up + GELU -> s1..s4
    gemm_bt<1, false><<<dim3(24, 32), 256, 0, stream>>>(s0, s5, b1, s1, M, FF, E, E, E, FF);
    // 7. FFN down partials z=4
    gemm_bt<3, false><<<dim3(6, 32, 4), 256, 0, stream>>>(
        s1, s5 + EF, nullptr, pp, M, E, FF, FF, FF, 0);
    // 8. out = res + Σpp + b2
    reduce_out<<<M, 256, 0, stream>>>(pp, 4, b2, res);
  } else {
    hipMemcpyAsync(d_out, x, ME * sizeof(float), hipMemcpyDeviceToDevice, stream);
    gemm_bt<2, false><<<dim3(6, 32, 2), 256, 0, stream>>>(
        s0, s4 + 3 * EE, bo, res, M, E, E, E, E, 0);
    ln_kernel<<<M, 256, 0, stream>>>(res, gamma, beta, s0, E);
    if (mid) {
      gemm_bt<1, false><<<dim3(24, 32), 256, 0, stream>>>(s0, s5, b1, s1, M, FF, E, E, E, FF);
      gemm_bt<2, false><<<dim3(6, 32, 4), 256, 0, stream>>>(
          s1, s5 + EF, b2, res, M, E, FF, FF, FF, 0);
    } else {
      gemm_bt<1, true><<<dim3(24, 32), 256, 0, stream>>>(s0, w1, b1, s1, M, FF, E, E, E, FF);
      cvt_multi<<<dim3(EF / 1024, 1), 256, 0, stream>>>(
          w2, nullptr, nullptr, nullptr, s0, nullptr, nullptr, nullptr);
      gemm_bt<2, false><<<dim3(6, 32, 4), 256, 0, stream>>>(
          s1, s0, b2, res, M, E, FF, FF, FF, 0);
    }
  }
}

// Round 6
// 310.554 us; speedup vs baseline: 1.3078x; 1.0654x over previous
//
#include <hip/hip_runtime.h>
#include <hip/hip_bf16.h>
#include <math.h>

typedef __bf16 bf16_8 __attribute__((ext_vector_type(8)));
typedef __bf16 bf16_4 __attribute__((ext_vector_type(4)));
typedef float f32x4 __attribute__((ext_vector_type(4)));

#define AS1 __attribute__((address_space(1)))
#define AS3 __attribute__((address_space(3)))

// ---------------------------------------------------------------- LayerNorm (fp32 in -> bf16 out)
__global__ __launch_bounds__(256) void ln_kernel(
    const float* __restrict__ x, const float* __restrict__ g,
    const float* __restrict__ b, __hip_bfloat16* __restrict__ out, int cols) {
  const int row = blockIdx.x;
  const int t = threadIdx.x;
  float loc[3];
  float s = 0.f, s2 = 0.f;
#pragma unroll
  for (int i = 0; i < 3; ++i) {
    float v = x[(size_t)row * cols + t + i * 256];
    loc[i] = v;
    s += v;
    s2 += v * v;
  }
#pragma unroll
  for (int off = 32; off; off >>= 1) {
    s += __shfl_down(s, off);
    s2 += __shfl_down(s2, off);
  }
  __shared__ float red[2][4];
  const int lane = t & 63, w = t >> 6;
  if (lane == 0) {
    red[0][w] = s;
    red[1][w] = s2;
  }
  __syncthreads();
  s = red[0][0] + red[0][1] + red[0][2] + red[0][3];
  s2 = red[1][0] + red[1][1] + red[1][2] + red[1][3];
  const float mu = s / cols;
  const float var = s2 / cols - mu * mu;
  const float rs = rsqrtf(var + 1e-5f);
  __hip_bfloat16* orow = out + (size_t)row * cols;
#pragma unroll
  for (int i = 0; i < 3; ++i) {
    int c = t + i * 256;
    orow[c] = __hip_bfloat16((loc[i] - mu) * rs * g[c] + b[c]);
  }
}

// ---------------------------------------------------------------- fused split-K reduce + residual + LN2
__global__ __launch_bounds__(256) void reduce_ln(
    const float* __restrict__ x, const float* __restrict__ part, int nz,
    const float* __restrict__ bias, const float* __restrict__ g,
    const float* __restrict__ b, float* __restrict__ res,
    __hip_bfloat16* __restrict__ yout) {
  const int row = blockIdx.x;
  const int t = threadIdx.x;
  const size_t zstride = (size_t)4096 * 768;
  float loc[3];
  float s = 0.f, s2 = 0.f;
#pragma unroll
  for (int i = 0; i < 3; ++i) {
    const int c = t + i * 256;
    const size_t off = (size_t)row * 768 + c;
    float v = x[off] + bias[c];
    for (int z = 0; z < nz; ++z) v += part[(size_t)z * zstride + off];
    res[off] = v;
    loc[i] = v;
    s += v;
    s2 += v * v;
  }
#pragma unroll
  for (int off = 32; off; off >>= 1) {
    s += __shfl_down(s, off);
    s2 += __shfl_down(s2, off);
  }
  __shared__ float red[2][4];
  const int lane = t & 63, w = t >> 6;
  if (lane == 0) {
    red[0][w] = s;
    red[1][w] = s2;
  }
  __syncthreads();
  s = red[0][0] + red[0][1] + red[0][2] + red[0][3];
  s2 = red[1][0] + red[1][1] + red[1][2] + red[1][3];
  const float mu = s / 768.f;
  const float var = s2 / 768.f - mu * mu;
  const float rs = rsqrtf(var + 1e-5f);
#pragma unroll
  for (int i = 0; i < 3; ++i) {
    const int c = t + i * 256;
    yout[(size_t)row * 768 + c] = __hip_bfloat16((loc[i] - mu) * rs * g[c] + b[c]);
  }
}

// ---------------------------------------------------------------- fused split-K reduce into residual (final out)
__global__ __launch_bounds__(256) void reduce_out(
    const float* __restrict__ part, int nz, const float* __restrict__ bias,
    float* __restrict__ res) {
  const int row = blockIdx.x;
  const int t = threadIdx.x;
  const size_t zstride = (size_t)4096 * 768;
#pragma unroll
  for (int i = 0; i < 3; ++i) {
    const int c = t + i * 256;
    const size_t off = (size_t)row * 768 + c;
    float v = res[off] + bias[c];
    for (int z = 0; z < nz; ++z) v += part[(size_t)z * zstride + off];
    res[off] = v;
  }
}

// ---------------------------------------------------------------- fp32 -> bf16 weight conversion
__global__ __launch_bounds__(256) void cvt_multi(
    const float* __restrict__ sa, const float* __restrict__ sb,
    const float* __restrict__ sc, const float* __restrict__ sd,
    __hip_bfloat16* __restrict__ da, __hip_bfloat16* __restrict__ db,
    __hip_bfloat16* __restrict__ dc, __hip_bfloat16* __restrict__ dd) {
  const float* src;
  __hip_bfloat16* dst;
  if (blockIdx.y == 0) { src = sa; dst = da; }
  else if (blockIdx.y == 1) { src = sb; dst = db; }
  else if (blockIdx.y == 2) { src = sc; dst = dc; }
  else { src = sd; dst = dd; }
  const size_t i = ((size_t)blockIdx.x * 256 + threadIdx.x) * 4;
  float4 f = *(const float4*)(src + i);
  bf16_4 o;
  o[0] = (__bf16)f.x; o[1] = (__bf16)f.y; o[2] = (__bf16)f.z; o[3] = (__bf16)f.w;
  *(bf16_4*)((__bf16*)dst + i) = o;
}

// ---------------------------------------------------------------- V pre-transpose + key-permute
// vt[bh][d][c] = v[b][s0 + k(c)][h*64+d] where within each 64-key block
// k(c) = 32*(c>>5) + 16*((c&7)>>2) + 4*((c>>3)&3) + (c&3).
// Makes the PV MFMA B-fragment equal the lane-held softmax C-layout fragments,
// so P never round-trips through LDS (verified round 5).
__global__ __launch_bounds__(256) void transpose_v(
    const __hip_bfloat16* __restrict__ v, __hip_bfloat16* __restrict__ vt) {
  const int S = 2048, E = 768, H = 12;
  const int s0 = blockIdx.x * 64;
  const int bh = blockIdx.y;
  const int b = bh / H, h = bh - b * H;
  __shared__ __align__(16) __bf16 T[64 * 72];
  const int tid = threadIdx.x;
#pragma unroll
  for (int u = 0; u < 2; ++u) {
    int i = tid + u * 256;
    int sr = i >> 3, c = i & 7;
    *(bf16_8*)(&T[sr * 72 + c * 8]) =
        *(const bf16_8*)(v + ((size_t)b * S + s0 + sr) * E + h * 64 + c * 8);
  }
  __syncthreads();
#pragma unroll
  for (int u = 0; u < 2; ++u) {
    int i = tid + u * 256;
    int dr = i >> 3, kc = i & 7;
    bf16_8 o;
#pragma unroll
    for (int e = 0; e < 8; ++e) {
      int k = 32 * (kc >> 2) + 16 * (e >> 2) + 4 * (kc & 3) + (e & 3);
      o[e] = T[k * 72 + dr];
    }
    *(bf16_8*)(vt + ((size_t)bh * 64 + dr) * S + s0 + kc * 8) = o;
  }
}

// ---------------------------------------------------------------- GEMM: C = A[M,K] @ B[N,K]^T
// m97 single-buffered 2-barrier structure (32 KB LDS -> 4 blocks/CU, the verified
// 874-TF loop) + T2 XOR-swizzled global_load_lds staging (conflict-free reads).
// Round-5 lesson: double-buffer at 64 KB LDS halves occupancy and loses more to
// latency than the prefetch gains (2 blocks/CU, 193 TF). Occupancy wins here.
template <int MODE, bool BF32>
__global__ __launch_bounds__(256) void gemm_bt(
    const __hip_bfloat16* __restrict__ A, const void* __restrict__ Bx,
    const float* __restrict__ bias, void* __restrict__ out,
    int M, int N, int K, int lda, int ldb, int ldout) {
  constexpr int BM = 128, BN = 128, BK = 64;
  constexpr int LDBP = BF32 ? 72 : BK;
  __shared__ __align__(16) __bf16 As[BM * BK];
  __shared__ __align__(16) __bf16 Bs[BN * LDBP];
  const int tid = threadIdx.x;
  const int m0 = blockIdx.y * BM;
  const int n0 = blockIdx.x * BN;
  const int wave = tid >> 6;
  const int lane = tid & 63;
  const int quad = lane >> 4;
  const int l16 = lane & 15;
  const int wm = (wave & 1) * 64;
  const int wn = (wave >> 1) * 64;

  int kbase = 0, kcnt = K;
  if constexpr (MODE == 2 || MODE == 3) {
    kcnt = K / gridDim.z;
    kbase = blockIdx.z * kcnt;
  }

  const int srow = lane >> 3;
  const int scol = ((lane & 7) ^ (srow & 7)) * 8;
  const __hip_bfloat16* Ap = A + (size_t)(m0 + wave * 8 + srow) * lda + kbase + scol;
  const __hip_bfloat16* Bpb = nullptr;
  const float* Bpf = nullptr;
  if constexpr (BF32)
    Bpf = (const float*)Bx;
  else
    Bpb = (const __hip_bfloat16*)Bx + (size_t)(n0 + wave * 8 + srow) * ldb + kbase + scol;

  f32x4 acc[4][4] = {};

  for (int k0 = 0; k0 < kcnt; k0 += BK) {
    __syncthreads();  // all waves done reading previous tile
#pragma unroll
    for (int u = 0; u < 4; ++u) {
      __builtin_amdgcn_global_load_lds(
          (const AS1 void*)(Ap + (size_t)(u * 32) * lda + k0),
          (AS3 void*)(&As[(u * 32 + wave * 8) * BK]), 16, 0, 0);
      if constexpr (!BF32)
        __builtin_amdgcn_global_load_lds(
            (const AS1 void*)(Bpb + (size_t)(u * 32) * ldb + k0),
            (AS3 void*)(&Bs[(u * 32 + wave * 8) * BK]), 16, 0, 0);
    }
    if constexpr (BF32) {
#pragma unroll
      for (int u = 0; u < 4; ++u) {
        int c = u * 256 + tid;
        int row = c >> 3, kc = c & 7;
        const float* src = Bpf + (size_t)(n0 + row) * ldb + kbase + k0 + kc * 8;
        float4 f0 = *(const float4*)src;
        float4 f1 = *(const float4*)(src + 4);
        bf16_8 bv;
        bv[0] = (__bf16)f0.x; bv[1] = (__bf16)f0.y; bv[2] = (__bf16)f0.z; bv[3] = (__bf16)f0.w;
        bv[4] = (__bf16)f1.x; bv[5] = (__bf16)f1.y; bv[6] = (__bf16)f1.z; bv[7] = (__bf16)f1.w;
        *(bf16_8*)(&Bs[row * LDBP + kc * 8]) = bv;
      }
    }
    __syncthreads();  // implicit vmcnt(0)/lgkm drain: tile staged
#pragma unroll
    for (int kk = 0; kk < 2; ++kk) {
      bf16_8 af[4], bfr[4];
#pragma unroll
      for (int i = 0; i < 4; ++i)
        af[i] = *(const bf16_8*)(
            &As[(wm + i * 16 + l16) * BK + (((kk * 4 + quad) ^ (l16 & 7)) * 8)]);
#pragma unroll
      for (int j = 0; j < 4; ++j) {
        if constexpr (BF32)
          bfr[j] = *(const bf16_8*)(&Bs[(wn + j * 16 + l16) * LDBP + kk * 32 + quad * 8]);
        else
          bfr[j] = *(const bf16_8*)(
              &Bs[(wn + j * 16 + l16) * BK + (((kk * 4 + quad) ^ (l16 & 7)) * 8)]);
      }
#pragma unroll
      for (int i = 0; i < 4; ++i)
#pragma unroll
        for (int j = 0; j < 4; ++j)
          acc[i][j] =
              __builtin_amdgcn_mfma_f32_16x16x32_bf16(af[i], bfr[j], acc[i][j], 0, 0, 0);
    }
  }

#pragma unroll
  for (int i = 0; i < 4; ++i) {
#pragma unroll
    for (int j = 0; j < 4; ++j) {
#pragma unroll
      for (int r = 0; r < 4; ++r) {
        const int row = m0 + wm + i * 16 + quad * 4 + r;
        const int col = n0 + wn + j * 16 + l16;
        const float v = acc[i][j][r];
        if constexpr (MODE == 0) {
          const int tsel = n0 / 768;
          const size_t idx = ((size_t)tsel * M + row) * 768 + (col - tsel * 768);
          ((__hip_bfloat16*)out)[idx] = __hip_bfloat16(v);
        } else if constexpr (MODE == 1) {
          float tt = v + bias[col];
          float gl = 0.5f * tt * (1.0f + erff(tt * 0.70710678118654752f));
          ((__hip_bfloat16*)out)[(size_t)row * ldout + col] = __hip_bfloat16(gl);
        } else if constexpr (MODE == 2) {
          float add = v + ((blockIdx.z == 0 && bias) ? bias[col] : 0.f);
          atomicAdd((float*)out + (size_t)row * 768 + col, add);
        } else {
          ((float*)out)[(size_t)blockIdx.z * M * 768 + (size_t)row * 768 + col] = v;
        }
      }
    }
  }
}

// ---------------------------------------------------------------- work counter
__global__ void zero_ctr(int* __restrict__ c) {
  if (threadIdx.x == 0) *c = 0;
}

// ---------------------------------------------------------------- MFMA flash attention (S^T / O^T form), v3
// (frozen from round 5 — in-register P, exp2 softmax, dbuf K/V, 1 barrier/tile)
#define ALDP 72
template <bool PRE_T>
__global__ __launch_bounds__(256) void attn_mfma(
    const __hip_bfloat16* __restrict__ qb, const __hip_bfloat16* __restrict__ kb,
    const __hip_bfloat16* __restrict__ vb, __hip_bfloat16* __restrict__ ob,
    int* __restrict__ ctr) {
  const int S = 2048, H = 12, E = 768;
  const int tid = threadIdx.x;
  const int wave = tid >> 6;
  const int lane = tid & 63;
  const int quad = lane >> 4;
  const int l16 = lane & 15;

  __shared__ __align__(16) __bf16 Ks[2][64 * 64];  // [key][d], chunk-XOR swizzled
  __shared__ __align__(16) __bf16 Vt[2][64 * 64];  // [d][key-permuted], chunk-XOR swizzled
  __shared__ int task;
  __bf16* ep = &Ks[0][0] + wave * 16 * ALDP;  // epilogue buffer aliases Ks

  const int srow8 = lane >> 3;
  const int csrc = ((lane & 7) ^ srow8) * 8;

  const float SCL = 0.18033688011112042f;  // (1/sqrt(64)) * log2(e)

  for (;;) {
    if (tid == 0) task = atomicAdd(ctr, 1);
    __syncthreads();
    const int t = task;
    if (t >= 24 * 32) return;
    const int qblk = 31 - (t / 24);
    const int bh = t - (t / 24) * 24;
    const int b = bh / H, h = bh - b * H;
    const int q0 = qblk * 64;
    const int qw = q0 + wave * 16;
    const size_t base = (size_t)b * S * E + (size_t)h * 64;

    auto STAGE = [&](int kts, int buf) {
      const int k0s = kts * 64;
#pragma unroll
      for (int u = 0; u < 2; ++u) {
        const int trow = wave * 16 + u * 8;
        __builtin_amdgcn_global_load_lds(
            (const AS1 void*)(kb + base + (size_t)(k0s + trow + srow8) * E + csrc),
            (AS3 void*)(&Ks[buf][trow * 64]), 16, 0, 0);
        if constexpr (PRE_T)
          __builtin_amdgcn_global_load_lds(
              (const AS1 void*)(vb + ((size_t)(bh * 64 + trow + srow8)) * S + k0s + csrc),
              (AS3 void*)(&Vt[buf][trow * 64]), 16, 0, 0);
      }
      if constexpr (!PRE_T) {
#pragma unroll
        for (int u = 0; u < 2; ++u) {
          int i = tid + u * 256;
          int kr = i & 63, dq = i >> 6;
          bf16_8 vv = *(const bf16_8*)(vb + base + (size_t)(k0s + kr) * E + dq * 8);
          const int c = 32 * (kr >> 5) + 8 * ((kr >> 2) & 3) + 4 * ((kr >> 4) & 1) + (kr & 3);
#pragma unroll
          for (int j = 0; j < 8; ++j) {
            int drow = dq * 8 + j;
            Vt[buf][drow * 64 + (((c >> 3) ^ (drow & 7)) * 8) + (c & 7)] = vv[j];
          }
        }
      }
    };

    bf16_8 qf[2];
#pragma unroll
    for (int s = 0; s < 2; ++s)
      qf[s] = *(const bf16_8*)(qb + base + (size_t)(qw + l16) * E + s * 32 + quad * 8);

    f32x4 o[4] = {};
    float mq = -1e30f, lq = 0.f;

    STAGE(0, 0);
    __syncthreads();
    int cur = 0;

    for (int kt = 0; kt <= qblk; ++kt) {
      const int k0 = kt * 64;
      if (kt < qblk) STAGE(kt + 1, cur ^ 1);

      f32x4 sc[4] = {};
      __builtin_amdgcn_s_setprio(1);
#pragma unroll
      for (int jj = 0; jj < 4; ++jj)
#pragma unroll
        for (int s = 0; s < 2; ++s) {
          bf16_8 kf = *(const bf16_8*)(
              &Ks[cur][(jj * 16 + l16) * 64 + (((s * 4 + quad) ^ (l16 & 7)) * 8)]);
          sc[jj] = __builtin_amdgcn_mfma_f32_16x16x32_bf16(kf, qf[s], sc[jj], 0, 0, 0);
        }
      __builtin_amdgcn_s_setprio(0);

#pragma unroll
      for (int jj = 0; jj < 4; ++jj)
#pragma unroll
        for (int r = 0; r < 4; ++r) sc[jj][r] *= SCL;
      if (kt == qblk) {
#pragma unroll
        for (int jj = 0; jj < 4; ++jj)
#pragma unroll
          for (int r = 0; r < 4; ++r)
            if ((k0 + jj * 16 + quad * 4 + r) > (qw + l16)) sc[jj][r] = -1e30f;
      }
      float mj[4];
#pragma unroll
      for (int jj = 0; jj < 4; ++jj)
        mj[jj] = fmaxf(fmaxf(sc[jj][0], sc[jj][1]), fmaxf(sc[jj][2], sc[jj][3]));
      float mx = fmaxf(fmaxf(mj[0], mj[1]), fmaxf(mj[2], mj[3]));
      mx = fmaxf(mx, __shfl_xor(mx, 16));
      mx = fmaxf(mx, __shfl_xor(mx, 32));
      const float mn = fmaxf(mq, mx);
      const float corr = exp2f(mq - mn);
      mq = mn;
      float sj[4];
#pragma unroll
      for (int jj = 0; jj < 4; ++jj) {
#pragma unroll
        for (int r = 0; r < 4; ++r) sc[jj][r] = exp2f(sc[jj][r] - mn);
        sj[jj] = (sc[jj][0] + sc[jj][1]) + (sc[jj][2] + sc[jj][3]);
      }
      float sum = (sj[0] + sj[1]) + (sj[2] + sj[3]);
      sum += __shfl_xor(sum, 16);
      sum += __shfl_xor(sum, 32);
      lq = lq * corr + sum;
#pragma unroll
      for (int nt2 = 0; nt2 < 4; ++nt2)
#pragma unroll
        for (int r = 0; r < 4; ++r) o[nt2][r] *= corr;

      bf16_8 pf[2];
#pragma unroll
      for (int s = 0; s < 2; ++s)
#pragma unroll
        for (int r = 0; r < 4; ++r) {
          pf[s][r] = (__bf16)sc[2 * s][r];
          pf[s][4 + r] = (__bf16)sc[2 * s + 1][r];
        }

      __builtin_amdgcn_s_setprio(1);
#pragma unroll
      for (int s = 0; s < 2; ++s)
#pragma unroll
        for (int dt = 0; dt < 4; ++dt) {
          bf16_8 vf = *(const bf16_8*)(
              &Vt[cur][(dt * 16 + l16) * 64 + (((s * 4 + quad) ^ (l16 & 7)) * 8)]);
          o[dt] = __builtin_amdgcn_mfma_f32_16x16x32_bf16(vf, pf[s], o[dt], 0, 0, 0);
        }
      __builtin_amdgcn_s_setprio(0);

      __syncthreads();
      cur ^= 1;
    }

    const float inv = 1.f / lq;
#pragma unroll
    for (int dt = 0; dt < 4; ++dt) {
      bf16_4 o4;
#pragma unroll
      for (int r = 0; r < 4; ++r) o4[r] = (__bf16)(o[dt][r] * inv);
      *(bf16_4*)(&ep[l16 * ALDP + dt * 16 + quad * 4]) = o4;
    }
#pragma unroll
    for (int u = 0; u < 2; ++u) {
      int j = lane + u * 64;
      int ql = j >> 3, ch = j & 7;
      bf16_8 ov = *(const bf16_8*)(&ep[ql * ALDP + ch * 8]);
      *(bf16_8*)(ob + base + (size_t)(qw + ql) * E + ch * 8) = ov;
    }
  }
}

// ---------------------------------------------------------------- launch
extern "C" void kernel_launch(void* const* d_in, const int* in_sizes, int n_in,
                              void* d_out, int out_size, void* d_ws, size_t ws_size,
                              hipStream_t stream) {
  const int Bv = 2, S = 2048, E = 768, FF = 3072;
  const int M = Bv * S;  // 4096
  const size_t ME = (size_t)M * E;
  const size_t EE = (size_t)E * E;
  const size_t EF = (size_t)E * FF;

  const float* x = (const float*)d_in[0];
  const float* wq = (const float*)d_in[1];
  const float* wk = (const float*)d_in[2];
  const float* wv = (const float*)d_in[3];
  const float* wo = (const float*)d_in[4];
  const float* bo = (const float*)d_in[5];
  const float* w1 = (const float*)d_in[6];
  const float* b1 = (const float*)d_in[7];
  const float* w2 = (const float*)d_in[8];
  const float* b2 = (const float*)d_in[9];
  const float* gamma = (const float*)d_in[10];
  const float* beta = (const float*)d_in[11];

  // ws layout: [ctr + 256B][s0..s4: 5×ME bf16][s5: w1|w2 bf16 2×EF][pp: 4×ME fp32]
  // vt (V^T, ME bf16) time-shares the pp region (attn finishes before partials).
  int* ctr = (int*)d_ws;
  __hip_bfloat16* slot = (__hip_bfloat16*)((char*)d_ws + 256);
  __hip_bfloat16* s0 = slot;
  __hip_bfloat16* s1 = slot + ME;
  __hip_bfloat16* s4 = slot + 4 * ME;
  __hip_bfloat16* s5 = slot + 5 * ME;
  float* pp = (float*)(slot + 5 * ME + 2 * EF);
  __hip_bfloat16* vt = (__hip_bfloat16*)pp;
  float* res = (float*)d_out;

  const size_t need_mid = 256 + (5 * ME + 2 * EF) * sizeof(__hip_bfloat16);
  const size_t need_full = need_mid + 4 * ME * sizeof(float);
  const bool full = ws_size >= need_full;
  const bool mid = ws_size >= need_mid;

  // 0. weights -> bf16
  cvt_multi<<<dim3(EE / 1024, 4), 256, 0, stream>>>(
      wq, wk, wv, wo, s4, s4 + EE, s4 + 2 * EE, s4 + 3 * EE);
  if (mid)
    cvt_multi<<<dim3(EF / 1024, 2), 256, 0, stream>>>(
        w1, w2, nullptr, nullptr, s5, s5 + EF, nullptr, nullptr);
  // 1. LN1
  ln_kernel<<<M, 256, 0, stream>>>(x, gamma, beta, s0, E);
  // 2. fused Q/K/V projection -> s1,s2,s3
  gemm_bt<0, false><<<dim3(18, 32), 256, 0, stream>>>(s0, s4, nullptr, s1, M, 2304, E, E, E, 0);
  // 3. causal flash attention -> s0
  zero_ctr<<<1, 64, 0, stream>>>(ctr);
  if (full) {
    transpose_v<<<dim3(32, 24), 256, 0, stream>>>(s1 + 2 * ME, vt);
    attn_mfma<true><<<768, 256, 0, stream>>>(s1, s1 + ME, vt, s0, ctr);
  } else {
    attn_mfma<false><<<768, 256, 0, stream>>>(s1, s1 + ME, s1 + 2 * ME, s0, ctr);
  }

  if (full) {
    // 4. attn-proj partials z=4
    gemm_bt<3, false><<<dim3(6, 32, 4), 256, 0, stream>>>(
        s0, s4 + 3 * EE, nullptr, pp, M, E, E, E, E, 0);
    // 5. res = x + Σpp + bo; y = LN2(res) -> s0
    reduce_ln<<<M, 256, 0, stream>>>(x, pp, 4, bo, gamma, beta, res, s0);
    // 6. FFN up + GELU -> s1..s4
    gemm_bt<1, false><<<dim3(24, 32), 256, 0, stream>>>(s0, s5, b1, s1, M, FF, E, E, E, FF);
    // 7. FFN down partials z=4
    gemm_bt<3, false><<<dim3(6, 32, 4), 256, 0, stream>>>(
        s1, s5 + EF, nullptr, pp, M, E, FF, FF, FF, 0);
    // 8. out = res + Σpp + b2
    reduce_out<<<M, 256, 0, stream>>>(pp, 4, b2, res);
  } else {
    hipMemcpyAsync(d_out, x, ME * sizeof(float), hipMemcpyDeviceToDevice, stream);
    gemm_bt<2, false><<<dim3(6, 32, 2), 256, 0, stream>>>(
        s0, s4 + 3 * EE, bo, res, M, E, E, E, E, 0);
    ln_kernel<<<M, 256, 0, stream>>>(res, gamma, beta, s0, E);
    if (mid) {
      gemm_bt<1, false><<<dim3(24, 32), 256, 0, stream>>>(s0, s5, b1, s1, M, FF, E, E, E, FF);
      gemm_bt<2, false><<<dim3(6, 32, 4), 256, 0, stream>>>(
          s1, s5 + EF, b2, res, M, E, FF, FF, FF, 0);
    } else {
      gemm_bt<1, true><<<dim3(24, 32), 256, 0, stream>>>(s0, w1, b1, s1, M, FF, E, E, E, FF);
      cvt_multi<<<dim3(EF / 1024, 1), 256, 0, stream>>>(
          w2, nullptr, nullptr, nullptr, s0, nullptr, nullptr, nullptr);
      gemm_bt<2, false><<<dim3(6, 32, 4), 256, 0, stream>>>(
          s1, s0, b2, res, M, E, FF, FF, FF, 0);
    }
  }
}